// Round 6
// baseline (18510.089 us; speedup 1.0000x reference)
//
#include <hip/hip_runtime.h>
#include <math.h>

// ---------------- problem constants ----------------
constexpr int Bz = 16;
constexpr int Sz = 512;
constexpr int Dz = 512;
constexpr int T1 = Sz + 1;     // 513
constexpr int TU = Sz * 3;     // 1536
constexpr float THRESHc = 1.0f;
constexpr float SM1c = 1.0f, NT1c = 0.0f;
constexpr float TAILc = 0.45f;
constexpr float SM2c = 0.25f, NT2c = 0.01f;

// LSTM persistent-kernel geometry: 32 WGs, each owns 16 h-dims of BOTH directions
constexpr int GD = 16;

// output layout (floats)
constexpr int EMB_OFF = 0;
constexpr int TOK_OFF = Bz * T1 * Dz;            // 4202496
constexpr int ALUT_OFF = TOK_OFF + Bz;           // 4202512
constexpr int USA_OFF = ALUT_OFF + Bz * T1;      // 4210720
constexpr int USP_OFF = USA_OFF + Bz * TU;       // 4235296

typedef short bf16x8 __attribute__((ext_vector_type(8)));
typedef float f32x4 __attribute__((ext_vector_type(4)));
typedef unsigned u32x4 __attribute__((ext_vector_type(4)));
typedef unsigned long long u64;

__device__ __forceinline__ float sigm(float x) { return 1.0f / (1.0f + expf(-x)); }
__device__ __forceinline__ float fsigm(float x) { return 1.0f / (1.0f + __expf(-x)); }
__device__ __forceinline__ float ftanh(float x) {
    float e = __expf(2.0f * x);
    return 1.0f - 2.0f / (e + 1.0f);
}
__device__ __forceinline__ unsigned short f2bf(float f) {
    unsigned u = __float_as_uint(f);
    return (unsigned short)((u + 0x7fffu + ((u >> 16) & 1u)) >> 16);
}

// ---------------- K0a: transpose conv_w -> wt[(i*3+k)*512 + d] ----------------
__global__ void k_transpose_convw(const float* __restrict__ cw, float* __restrict__ wt) {
    __shared__ float tile[64][65];
    int dt = blockIdx.x * 64, ct = blockIdx.y * 64;
    int tx = threadIdx.x & 63, ty = threadIdx.x >> 6;
    for (int r = ty; r < 64; r += 4)
        tile[r][tx] = cw[(dt + r) * 1536 + ct + tx];
    __syncthreads();
    for (int r = ty; r < 64; r += 4)
        wt[(ct + r) * 512 + dt + tx] = tile[tx][r];
}

// ---------------- K0b: transpose up_w -> upt[(k*512+o)*512 + i] ----------------
__global__ void k_transpose_upw(const float* __restrict__ uw, float* __restrict__ upt) {
    __shared__ float tile[64][65];
    int it = blockIdx.x * 64, ct = blockIdx.y * 64;
    int tx = threadIdx.x & 63, ty = threadIdx.x >> 6;
    for (int r = ty; r < 64; r += 4)
        tile[r][tx] = uw[(it + r) * 1536 + ct + tx];
    __syncthreads();
    for (int r = ty; r < 64; r += 4) {
        int c = ct + r;
        int k = c % 3, o = c / 3;
        upt[(k * 512 + o) * 512 + it + tx] = tile[tx][r];
    }
}

// ---------------- K0c: gconst[dir*2048+g] = b_ih+b_hh+sum_o up_b[o]*w_ih[g][o] ----------------
__global__ void k_gconst(const float* __restrict__ wih_f, const float* __restrict__ bih_f,
                         const float* __restrict__ bhh_f, const float* __restrict__ wih_b,
                         const float* __restrict__ bih_b, const float* __restrict__ bhh_b,
                         const float* __restrict__ upb, float* __restrict__ gconst) {
    int g = blockIdx.x * 256 + threadIdx.x;   // 0..4095
    int dir = g >> 11, gg = g & 2047;
    const float* wih = dir ? wih_b : wih_f;
    const float* bi = dir ? bih_b : bih_f;
    const float* bh = dir ? bhh_b : bhh_f;
    float s = bi[gg] + bh[gg];
    const float4* w4 = (const float4*)(wih + (size_t)gg * 512);
    const float4* u4 = (const float4*)upb;
    for (int o = 0; o < 128; ++o) {
        float4 w = w4[o], u = u4[o];
        s += w.x * u.x + w.y * u.y + w.z * u.z + w.w * u.w;
    }
    gconst[g] = s;
}

// ---------------- K1: M[(dir*3+k)*2048+g][i] = sum_o wih[g][o]*upt[k][o][i], bf16 ----------------
__global__ void k_M(const float* __restrict__ wih_f, const float* __restrict__ wih_b,
                    const float* __restrict__ upt, unsigned short* __restrict__ Mh) {
    __shared__ float As[32][68];
    __shared__ float Bs[32][68];
    int z = blockIdx.z;
    int dir = z / 3, k = z % 3;
    const float* A = dir ? wih_b : wih_f;
    const float* Bt = upt + (size_t)k * 262144;
    int g0 = blockIdx.y * 64, i0 = blockIdx.x * 64;
    int tid = threadIdx.x;
    int tx = tid & 15, ty = tid >> 4;
    float acc[4][4] = {};
    for (int k0 = 0; k0 < 512; k0 += 32) {
#pragma unroll
        for (int e = 0; e < 8; ++e) {
            int idx = e * 256 + tid;
            int ko = idx & 31, gl = idx >> 5;
            As[ko][gl] = A[(size_t)(g0 + gl) * 512 + k0 + ko];
        }
#pragma unroll
        for (int e = 0; e < 8; ++e) {
            int idx = e * 256 + tid;
            int il = idx & 63, ko = idx >> 6;
            Bs[ko][il] = Bt[(size_t)(k0 + ko) * 512 + i0 + il];
        }
        __syncthreads();
#pragma unroll
        for (int ko = 0; ko < 32; ++ko) {
            float4 a = *(const float4*)&As[ko][ty * 4];
            float4 b = *(const float4*)&Bs[ko][tx * 4];
            acc[0][0] += a.x * b.x; acc[0][1] += a.x * b.y; acc[0][2] += a.x * b.z; acc[0][3] += a.x * b.w;
            acc[1][0] += a.y * b.x; acc[1][1] += a.y * b.y; acc[1][2] += a.y * b.z; acc[1][3] += a.y * b.w;
            acc[2][0] += a.z * b.x; acc[2][1] += a.z * b.y; acc[2][2] += a.z * b.z; acc[2][3] += a.z * b.w;
            acc[3][0] += a.w * b.x; acc[3][1] += a.w * b.y; acc[3][2] += a.w * b.z; acc[3][3] += a.w * b.w;
        }
        __syncthreads();
    }
#pragma unroll
    for (int r = 0; r < 4; ++r) {
        ushort4 wh;
        wh.x = f2bf(acc[r][0]); wh.y = f2bf(acc[r][1]);
        wh.z = f2bf(acc[r][2]); wh.w = f2bf(acc[r][3]);
        *(ushort4*)&Mh[((size_t)(z * 2048 + g0 + ty * 4 + r)) * 512 + i0 + tx * 4] = wh;
    }
}

// ---------------- K1b: hidden -> bf16 ----------------
__global__ void k_Hbf(const float* __restrict__ hidden, unsigned short* __restrict__ Hs) {
    int i = blockIdx.x * 256 + threadIdx.x;   // handles 4 floats
    float4 v = *(const float4*)&hidden[(size_t)i * 4];
    ushort4 h4;
    h4.x = f2bf(v.x); h4.y = f2bf(v.y); h4.z = f2bf(v.z); h4.w = f2bf(v.w);
    *(ushort4*)&Hs[(size_t)i * 4] = h4;
}

// ---------------- K2: conv1d(pad1,k3)+relu then dot(out_w)+sigmoid -> alphas_s[b][s] ----------------
__global__ void k_conv_alpha(const float* __restrict__ hidden, const float* __restrict__ wt,
                             const float* __restrict__ cb, const float* __restrict__ ow,
                             const float* __restrict__ ob, const float* __restrict__ mask,
                             float* __restrict__ alph_s) {
    __shared__ float hs[18 * 512];
    __shared__ float red[16][257];
    int b = blockIdx.x, s0 = blockIdx.y * 16;
    int tid = threadIdx.x;
#pragma unroll
    for (int e = 0; e < 36; ++e) {
        int idx = e * 256 + tid;
        int r = idx >> 9, i = idx & 511;
        int s = s0 + r - 1;
        hs[idx] = (s >= 0 && s < Sz) ? hidden[((size_t)b * Sz + s) * Dz + i] : 0.f;
    }
    __syncthreads();
    float acc0[16] = {}, acc1[16] = {};
    int d0 = tid, d1 = tid + 256;
    for (int i = 0; i < 512; ++i) {
        float w00 = wt[(i * 3 + 0) * 512 + d0];
        float w01 = wt[(i * 3 + 1) * 512 + d0];
        float w02 = wt[(i * 3 + 2) * 512 + d0];
        float w10 = wt[(i * 3 + 0) * 512 + d1];
        float w11 = wt[(i * 3 + 1) * 512 + d1];
        float w12 = wt[(i * 3 + 2) * 512 + d1];
        float hv[18];
#pragma unroll
        for (int r = 0; r < 18; ++r) hv[r] = hs[r * 512 + i];
#pragma unroll
        for (int j = 0; j < 16; ++j) {
            acc0[j] += hv[j] * w00 + hv[j + 1] * w01 + hv[j + 2] * w02;
            acc1[j] += hv[j] * w10 + hv[j + 1] * w11 + hv[j + 2] * w12;
        }
    }
    float cb0 = cb[d0], cb1 = cb[d1], ow0 = ow[d0], ow1 = ow[d1];
#pragma unroll
    for (int j = 0; j < 16; ++j)
        red[j][tid] = fmaxf(acc0[j] + cb0, 0.f) * ow0 + fmaxf(acc1[j] + cb1, 0.f) * ow1;
    __syncthreads();
    for (int off = 128; off >= 1; off >>= 1) {
        if (tid < off) {
#pragma unroll
            for (int j = 0; j < 16; ++j) red[j][tid] += red[j][tid + off];
        }
        __syncthreads();
    }
    if (tid < 16) {
        float v = red[tid][0] + ob[0];
        float a = sigm(v);
        a = fmaxf(a * SM1c - NT1c, 0.f);
        a *= mask[b * Sz + s0 + tid];
        alph_s[b * Sz + s0 + tid] = a;
    }
}

// ---------------- K3: CIF scalar scan (serial per batch) ----------------
__global__ void k_cif_scan(const float* __restrict__ alph_s, const float* __restrict__ mask,
                           float* __restrict__ out, float* __restrict__ sc_cur,
                           float* __restrict__ sc_res, int* __restrict__ sc_dst) {
    __shared__ float sa[16][T1];
    int tid = threadIdx.x;
    for (int idx = tid; idx < 16 * T1; idx += 256) {
        int b = idx / T1, t = idx % T1;
        float a = (t < Sz) ? alph_s[b * Sz + t] : 0.f;
        float mp = (t == 0) ? 1.f : mask[b * Sz + t - 1];
        float mc = (t < Sz) ? mask[b * Sz + t] : 0.f;
        sa[b][t] = a + (mp - mc) * TAILc;
    }
    __syncthreads();
    if (tid < 16) {
        int b = tid;
        float integ = 0.f, sum = 0.f;
        int nf = 0;
        for (int t = 0; t < T1; ++t) {
            float a = sa[b][t];
            out[ALUT_OFF + b * T1 + t] = a;
            sum += a;
            float dist = 1.f - integ;
            integ += a;
            bool fire = (integ >= THRESHc);
            float cur = fire ? dist : a;
            sc_cur[b * T1 + t] = cur;
            sc_res[b * T1 + t] = fire ? (a - cur) : 0.f;
            sc_dst[b * T1 + t] = fire ? (nf++) : -1;
            if (fire) integ -= 1.f;
        }
        out[TOK_OFF + b] = floorf(sum);
    }
}

// ---------------- K4: CIF frame accumulation / scatter ----------------
__global__ void k_cif_frames(const float* __restrict__ hidden, const float* __restrict__ sc_cur,
                             const float* __restrict__ sc_res, const int* __restrict__ sc_dst,
                             float* __restrict__ out) {
    __shared__ float cu[T1], re[T1];
    __shared__ int dsx[T1];
    int b = blockIdx.x, d = blockIdx.y * 256 + threadIdx.x;
    for (int t = threadIdx.x; t < T1; t += 256) {
        cu[t] = sc_cur[b * T1 + t];
        re[t] = sc_res[b * T1 + t];
        dsx[t] = sc_dst[b * T1 + t];
    }
    __syncthreads();
    float frame = 0.f;
    for (int t = 0; t < T1; ++t) {
        float ht = (t < Sz) ? hidden[((size_t)b * Sz + t) * Dz + d] : 0.f;
        float f = frame + cu[t] * ht;
        int dst = dsx[t];
        if (dst >= 0) {
            out[EMB_OFF + ((size_t)b * T1 + dst) * Dz + d] = f;
            frame = re[t] * ht;
        } else {
            frame = f;
        }
    }
}

// ---------------- K5: persistent cooperative BiLSTM v6 ----------------
// 32 WGs handle BOTH directions (fine interleave hides exchange RT under the
// other chain's compute). h exchange via tag-embedded 16B units: gather IS the
// poll (load + validate + retry). No counters, no producer-side drain.
__global__ void __launch_bounds__(256, 1)
k_lstm(const unsigned short* __restrict__ Mh, const unsigned short* __restrict__ Hs,
       const float* __restrict__ whh_f, const float* __restrict__ whh_b,
       const float* __restrict__ gconst, const float* __restrict__ w2,
       u32x4* exch, float* part) {
    __shared__ unsigned short hbuf[16 * 512];   // swizzled h (one direction at a time)
    __shared__ float xch[3 * 256];

    const int slice = blockIdx.x;               // 0..31
    const int d0 = slice * GD;
    const int tid = threadIdx.x;
    const int wv = tid >> 6;                    // wave = gate (0:i 1:f 2:g 3:o)
    const int l = tid & 63;
    const int colb = l & 15;                    // batch
    const int khi = l >> 4;

    // one-time: W_hh bf16 fragments for BOTH directions in registers
    bf16x8 whF[16], whB[16];
    {
        const float* wrF = whh_f + (size_t)(wv * 512 + d0 + colb) * 512 + khi * 8;
        const float* wrB = whh_b + (size_t)(wv * 512 + d0 + colb) * 512 + khi * 8;
#pragma unroll
        for (int m = 0; m < 16; ++m) {
            float4 a = *(const float4*)(wrF + m * 32);
            float4 b = *(const float4*)(wrF + m * 32 + 4);
            union { unsigned short u[8]; bf16x8 v; } t1;
            t1.u[0] = f2bf(a.x); t1.u[1] = f2bf(a.y); t1.u[2] = f2bf(a.z); t1.u[3] = f2bf(a.w);
            t1.u[4] = f2bf(b.x); t1.u[5] = f2bf(b.y); t1.u[6] = f2bf(b.z); t1.u[7] = f2bf(b.w);
            whF[m] = t1.v;
            a = *(const float4*)(wrB + m * 32);
            b = *(const float4*)(wrB + m * 32 + 4);
            union { unsigned short u[8]; bf16x8 v; } t2;
            t2.u[0] = f2bf(a.x); t2.u[1] = f2bf(a.y); t2.u[2] = f2bf(a.z); t2.u[3] = f2bf(a.w);
            t2.u[4] = f2bf(b.x); t2.u[5] = f2bf(b.y); t2.u[6] = f2bf(b.z); t2.u[7] = f2bf(b.w);
            whB[m] = t2.v;
        }
    }

    f32x4 biasF, biasB;
    float w2F[4], w2B[4];
    f32x4 cstF = {0.f, 0.f, 0.f, 0.f}, cstB = {0.f, 0.f, 0.f, 0.f};
#pragma unroll
    for (int j = 0; j < 4; ++j) {
        biasF[j] = gconst[0 * 2048 + wv * 512 + d0 + khi * 4 + j];
        biasB[j] = gconst[1 * 2048 + wv * 512 + d0 + khi * 4 + j];
        w2F[j] = w2[0 * 512 + d0 + khi * 4 + j];
        w2B[j] = w2[1 * 512 + d0 + khi * 4 + j];
    }

    auto idot = [&](int dir, int n) -> f32x4 {
        int t = dir ? (TU - 1 - n) : n;
        int s = t / 3, k = t - 3 * s;
        const unsigned short* ma = Mh + ((size_t)((dir * 3 + k) * 2048 + wv * 512 + d0 + colb)) * 512 + khi * 8;
        const unsigned short* xa = Hs + ((size_t)(colb * 512 + s)) * 512 + khi * 8;
        f32x4 a = dir ? biasB : biasF;
#pragma unroll
        for (int m = 0; m < 16; ++m) {
            bf16x8 A = *(const bf16x8*)(ma + m * 32);
            bf16x8 B = *(const bf16x8*)(xa + m * 32);
            a = __builtin_amdgcn_mfma_f32_16x16x32_bf16(A, B, a, 0, 0, 0);
        }
        return a;
    };

    u32x4 gS[8];   // shared staging for both directions (live windows disjoint)

    auto issue8 = [&](int d, int n) {
        const u32x4* base = exch + (size_t)((d * 2 + ((n - 1) & 1)) * 2048) + tid * 8;
#pragma unroll
        for (int j = 0; j < 8; ++j)
            asm volatile("global_load_dwordx4 %0, %1, off sc0 sc1"
                         : "=v"(gS[j]) : "v"(base + j));
    };
    auto waitok = [&](int d, int n) {
        const u32x4* base = exch + (size_t)((d * 2 + ((n - 1) & 1)) * 2048) + tid * 8;
        unsigned tag = (unsigned)n;
        int it = 0;
        while (true) {
            asm volatile("s_waitcnt vmcnt(0)" ::: "memory");
            bool ok = true;
#pragma unroll
            for (int j = 0; j < 8; ++j) ok = ok && (gS[j][2] == tag);
            if (__ballot(!ok) == 0ull) break;
            if (++it > (1 << 13)) break;
            __builtin_amdgcn_s_sleep(1);
#pragma unroll
            for (int j = 0; j < 8; ++j)
                asm volatile("global_load_dwordx4 %0, %1, off sc0 sc1"
                             : "=v"(gS[j]) : "v"(base + j));
        }
    };
    auto unpack = [&]() {
#pragma unroll
        for (int j = 0; j < 8; ++j) {
            int u = tid * 8 + j;
            int batch = u & 15;
            int gq = u >> 4;   // 4-dim granule index 0..127
            int sw = (((gq >> 1) ^ (batch & 7)) << 3) + ((gq & 1) << 2);
            u64 q = (u64)gS[j][0] | ((u64)gS[j][1] << 32);
            *(u64*)&hbuf[batch * 512 + sw] = q;
        }
    };
    auto hhdot = [&](const bf16x8* wh, f32x4 acc) -> f32x4 {
#pragma unroll
        for (int m = 0; m < 16; ++m) {
            bf16x8 B = *(const bf16x8*)&hbuf[colb * 512 + (((m * 4 + khi) ^ (colb & 7)) << 3)];
            acc = __builtin_amdgcn_mfma_f32_16x16x32_bf16(wh[m], B, acc, 0, 0, 0);
        }
        return acc;
    };
    auto cellphase = [&](f32x4 acc, f32x4& cst, const float* w2v, int d, int n, int t) {
        if (wv != 0) {
#pragma unroll
            for (int j = 0; j < 4; ++j)
                xch[(wv - 1) * 256 + (khi * 4 + j) * 16 + colb] = acc[j];
        }
        __syncthreads();
        if (wv == 0) {
            unsigned short h4[4];
            float p = 0.f;
#pragma unroll
            for (int j = 0; j < 4; ++j) {
                int rr = khi * 4 + j;
                float gi = acc[j];
                float gf = xch[0 * 256 + rr * 16 + colb];
                float gg = xch[1 * 256 + rr * 16 + colb];
                float go = xch[2 * 256 + rr * 16 + colb];
                float c2 = fsigm(gf) * cst[j] + fsigm(gi) * ftanh(gg);
                cst[j] = c2;
                float h = fsigm(go) * ftanh(c2);
                h4[j] = f2bf(h);
                p += h * w2v[j];
            }
            unsigned lo = (unsigned)h4[0] | ((unsigned)h4[1] << 16);
            unsigned hi = (unsigned)h4[2] | ((unsigned)h4[3] << 16);
            u32x4 outv = { lo, hi, (unsigned)(n + 1), (unsigned)(n + 1) };
            u32x4* dst = exch + (size_t)((d * 2 + (n & 1)) * 2048 + slice * 64 + l);
            asm volatile("global_store_dwordx4 %0, %1, off sc0 sc1"
                         :: "v"(dst), "v"(outv) : "memory");
            p += __shfl_xor(p, 16);
            p += __shfl_xor(p, 32);
            if (l < 16)
                part[((size_t)((d * 32 + slice) * 16) + l) * TU + t] = p;
        }
    };

    f32x4 accF = idot(0, 0);
    f32x4 accB = idot(1, 0);

    for (int n = 0; n < TU; ++n) {
        // ========== FWD step n ==========
        if (n > 0) {
            waitok(0, n);           // gS issued at prev iteration's bwd tail
            unpack();
            __syncthreads();
            accF = hhdot(whF, accF);
        }
        cellphase(accF, cstF, w2F, 0, n, n);
        if (n > 0) issue8(1, n);    // gather h_b[n-1]; RT hides under idot_f
        if (n + 1 < TU) accF = idot(0, n + 1);
        // ========== BWD step n ==========
        if (n > 0) {
            waitok(1, n);
            unpack();
            __syncthreads();
            accB = hhdot(whB, accB);
        }
        cellphase(accB, cstB, w2B, 1, n, TU - 1 - n);
        if (n + 1 < TU) {
            issue8(0, n + 1);       // gather h_f[n]; RT hides under idot_b + next fwd
            accB = idot(1, n + 1);
        }
    }
}

// ---------------- K6: reduce us partials, activation, pre-norm ----------------
__global__ void k_us_reduce(const float* __restrict__ part, const float* __restrict__ ob2,
                            const float* __restrict__ mask, float* __restrict__ usA,
                            float* __restrict__ csum) {
    int b = blockIdx.x, ch = blockIdx.y;
    int t = ch * 256 + threadIdx.x;
    float s = 0.f;
#pragma unroll 8
    for (int p = 0; p < 64; ++p) s += part[((size_t)p * Bz + b) * TU + t];
    float u = sigm(s + ob2[0]);
    float ua = fmaxf(u * SM2c - NT2c, 0.f) * mask[b * Sz + t / 3];
    usA[b * TU + t] = ua;
    __shared__ float red[256];
    red[threadIdx.x] = ua;
    __syncthreads();
    for (int off = 128; off >= 1; off >>= 1) {
        if (threadIdx.x < off) red[threadIdx.x] += red[threadIdx.x + off];
        __syncthreads();
    }
    if (threadIdx.x == 0) csum[b * 6 + ch] = red[0];
}

// ---------------- K7: normalize + peak scan (serial per batch) ----------------
__global__ void k_us_scan(const float* __restrict__ usA, const float* __restrict__ csum,
                          float* __restrict__ out) {
    __shared__ float ubuf[TU];
    int b = blockIdx.x;
    for (int t = threadIdx.x; t < TU; t += 64) ubuf[t] = usA[b * TU + t];
    __syncthreads();
    if (threadIdx.x == 0) {
        float tot = 0.f;
        for (int c = 0; c < 6; ++c) tot += csum[b * 6 + c];
        float scale = out[TOK_OFF + b] / tot;
        float integ = 0.f;
        const float th = THRESHc - 0.0001f;
        for (int t = 0; t < TU; ++t) {
            float ua = ubuf[t] * scale;
            out[USA_OFF + b * TU + t] = ua;
            integ += ua;
            out[USP_OFF + b * TU + t] = integ;
            if (integ >= th) integ -= th;
        }
    }
}

// ---------------- host ----------------
extern "C" void kernel_launch(void* const* d_in, const int* in_sizes, int n_in,
                              void* d_out, int out_size, void* d_ws, size_t ws_size,
                              hipStream_t stream) {
    const float* hidden = (const float*)d_in[0];
    const float* mask   = (const float*)d_in[1];
    const float* conv_w = (const float*)d_in[2];
    const float* conv_b = (const float*)d_in[3];
    const float* out_w  = (const float*)d_in[4];
    const float* out_b  = (const float*)d_in[5];
    const float* up_w   = (const float*)d_in[6];
    const float* up_b   = (const float*)d_in[7];
    const float* w_ih_f = (const float*)d_in[8];
    const float* w_hh_f = (const float*)d_in[9];
    const float* b_ih_f = (const float*)d_in[10];
    const float* b_hh_f = (const float*)d_in[11];
    const float* w_ih_b = (const float*)d_in[12];
    const float* w_hh_b = (const float*)d_in[13];
    const float* b_ih_b = (const float*)d_in[14];
    const float* b_hh_b = (const float*)d_in[15];
    const float* out2_w = (const float*)d_in[16];
    const float* out2_b = (const float*)d_in[17];
    float* out = (float*)d_out;
    float* ws = (float*)d_ws;

    // workspace layout (float slots), total ~8.48M floats = 33.9 MB
    float* wt     = ws + 0;              // 786,432
    float* upt    = ws + 786432;         // 786,432
    float* part   = ws + 1572864;        // 1,572,864
    float* gconst = ws + 3145728;        // 4096
    float* alph_s = ws + 3149824;        // 8192
    float* sc_cur = ws + 3158016;        // 8208
    float* sc_res = ws + 3166224;        // 8208
    int*   sc_dst = (int*)(ws + 3174432);            // 8208
    float* usA    = ws + 3182640;        // 24576
    float* csum   = ws + 3207216;        // 96
    unsigned short* Mh = (unsigned short*)(ws + 3207312);   // 6,291,456 shorts
    unsigned short* Hs = (unsigned short*)(ws + 6353040);   // 4,194,304 shorts
    u32x4* exch   = (u32x4*)(ws + 8450192);          // 8192 units x 16 B = 128 KB

    hipMemsetAsync(out, 0, (size_t)Bz * T1 * Dz * sizeof(float), stream);   // embeds region
    hipMemsetAsync(exch, 0, 8192 * 16, stream);

    k_transpose_convw<<<dim3(8, 24), 256, 0, stream>>>(conv_w, wt);
    k_transpose_upw<<<dim3(8, 24), 256, 0, stream>>>(up_w, upt);
    k_gconst<<<16, 256, 0, stream>>>(w_ih_f, b_ih_f, b_hh_f, w_ih_b, b_ih_b, b_hh_b, up_b, gconst);
    k_M<<<dim3(8, 32, 6), 256, 0, stream>>>(w_ih_f, w_ih_b, upt, Mh);
    k_Hbf<<<4096, 256, 0, stream>>>(hidden, Hs);
    k_conv_alpha<<<dim3(16, 32), 256, 0, stream>>>(hidden, wt, conv_b, out_w, out_b, mask, alph_s);
    k_cif_scan<<<1, 256, 0, stream>>>(alph_s, mask, out, sc_cur, sc_res, sc_dst);
    k_cif_frames<<<dim3(16, 2), 256, 0, stream>>>(hidden, sc_cur, sc_res, sc_dst, out);

    {
        void* args[] = { (void*)&Mh, (void*)&Hs, (void*)&w_hh_f, (void*)&w_hh_b,
                         (void*)&gconst, (void*)&out2_w, (void*)&exch, (void*)&part };
        hipLaunchCooperativeKernel(reinterpret_cast<void*>(&k_lstm), dim3(32), dim3(256),
                                   args, 0, stream);
    }

    k_us_reduce<<<dim3(16, 6), 256, 0, stream>>>(part, out2_b, mask, usA, csum);
    k_us_scan<<<16, 64, 0, stream>>>(usA, csum, out);
}

// Round 7
// 13534.419 us; speedup vs baseline: 1.3676x; 1.3676x over previous
//
#include <hip/hip_runtime.h>
#include <math.h>

// ---------------- problem constants ----------------
constexpr int Bz = 16;
constexpr int Sz = 512;
constexpr int Dz = 512;
constexpr int T1 = Sz + 1;     // 513
constexpr int TU = Sz * 3;     // 1536
constexpr float THRESHc = 1.0f;
constexpr float SM1c = 1.0f, NT1c = 0.0f;
constexpr float TAILc = 0.45f;
constexpr float SM2c = 0.25f, NT2c = 0.01f;

// LSTM persistent-kernel geometry: 64 WGs (32 per direction), 16 h-dims each
constexpr int GD = 16;

// output layout (floats)
constexpr int EMB_OFF = 0;
constexpr int TOK_OFF = Bz * T1 * Dz;            // 4202496
constexpr int ALUT_OFF = TOK_OFF + Bz;           // 4202512
constexpr int USA_OFF = ALUT_OFF + Bz * T1;      // 4210720
constexpr int USP_OFF = USA_OFF + Bz * TU;       // 4235296

typedef short bf16x8 __attribute__((ext_vector_type(8)));
typedef float f32x4 __attribute__((ext_vector_type(4)));
typedef unsigned u32x4 __attribute__((ext_vector_type(4)));
typedef unsigned long long u64;

__device__ __forceinline__ float sigm(float x) { return 1.0f / (1.0f + expf(-x)); }
__device__ __forceinline__ float fsigm(float x) { return 1.0f / (1.0f + __expf(-x)); }
__device__ __forceinline__ float ftanh(float x) {
    float e = __expf(2.0f * x);
    return 1.0f - 2.0f / (e + 1.0f);
}
__device__ __forceinline__ unsigned short f2bf(float f) {
    unsigned u = __float_as_uint(f);
    return (unsigned short)((u + 0x7fffu + ((u >> 16) & 1u)) >> 16);
}

// ---------------- K0a: transpose conv_w -> wt[(i*3+k)*512 + d] ----------------
__global__ void k_transpose_convw(const float* __restrict__ cw, float* __restrict__ wt) {
    __shared__ float tile[64][65];
    int dt = blockIdx.x * 64, ct = blockIdx.y * 64;
    int tx = threadIdx.x & 63, ty = threadIdx.x >> 6;
    for (int r = ty; r < 64; r += 4)
        tile[r][tx] = cw[(dt + r) * 1536 + ct + tx];
    __syncthreads();
    for (int r = ty; r < 64; r += 4)
        wt[(ct + r) * 512 + dt + tx] = tile[tx][r];
}

// ---------------- K0b: transpose up_w -> upt[(k*512+o)*512 + i] ----------------
__global__ void k_transpose_upw(const float* __restrict__ uw, float* __restrict__ upt) {
    __shared__ float tile[64][65];
    int it = blockIdx.x * 64, ct = blockIdx.y * 64;
    int tx = threadIdx.x & 63, ty = threadIdx.x >> 6;
    for (int r = ty; r < 64; r += 4)
        tile[r][tx] = uw[(it + r) * 1536 + ct + tx];
    __syncthreads();
    for (int r = ty; r < 64; r += 4) {
        int c = ct + r;
        int k = c % 3, o = c / 3;
        upt[(k * 512 + o) * 512 + it + tx] = tile[tx][r];
    }
}

// ---------------- K0c: gconst[dir*2048+g] = b_ih+b_hh+sum_o up_b[o]*w_ih[g][o] ----------------
__global__ void k_gconst(const float* __restrict__ wih_f, const float* __restrict__ bih_f,
                         const float* __restrict__ bhh_f, const float* __restrict__ wih_b,
                         const float* __restrict__ bih_b, const float* __restrict__ bhh_b,
                         const float* __restrict__ upb, float* __restrict__ gconst) {
    int g = blockIdx.x * 256 + threadIdx.x;   // 0..4095
    int dir = g >> 11, gg = g & 2047;
    const float* wih = dir ? wih_b : wih_f;
    const float* bi = dir ? bih_b : bih_f;
    const float* bh = dir ? bhh_b : bhh_f;
    float s = bi[gg] + bh[gg];
    const float4* w4 = (const float4*)(wih + (size_t)gg * 512);
    const float4* u4 = (const float4*)upb;
    for (int o = 0; o < 128; ++o) {
        float4 w = w4[o], u = u4[o];
        s += w.x * u.x + w.y * u.y + w.z * u.z + w.w * u.w;
    }
    gconst[g] = s;
}

// ---------------- K1: M[(dir*3+k)*2048+g][i] = sum_o wih[g][o]*upt[k][o][i], bf16 ----------------
__global__ void k_M(const float* __restrict__ wih_f, const float* __restrict__ wih_b,
                    const float* __restrict__ upt, unsigned short* __restrict__ Mh) {
    __shared__ float As[32][68];
    __shared__ float Bs[32][68];
    int z = blockIdx.z;
    int dir = z / 3, k = z % 3;
    const float* A = dir ? wih_b : wih_f;
    const float* Bt = upt + (size_t)k * 262144;
    int g0 = blockIdx.y * 64, i0 = blockIdx.x * 64;
    int tid = threadIdx.x;
    int tx = tid & 15, ty = tid >> 4;
    float acc[4][4] = {};
    for (int k0 = 0; k0 < 512; k0 += 32) {
#pragma unroll
        for (int e = 0; e < 8; ++e) {
            int idx = e * 256 + tid;
            int ko = idx & 31, gl = idx >> 5;
            As[ko][gl] = A[(size_t)(g0 + gl) * 512 + k0 + ko];
        }
#pragma unroll
        for (int e = 0; e < 8; ++e) {
            int idx = e * 256 + tid;
            int il = idx & 63, ko = idx >> 6;
            Bs[ko][il] = Bt[(size_t)(k0 + ko) * 512 + i0 + il];
        }
        __syncthreads();
#pragma unroll
        for (int ko = 0; ko < 32; ++ko) {
            float4 a = *(const float4*)&As[ko][ty * 4];
            float4 b = *(const float4*)&Bs[ko][tx * 4];
            acc[0][0] += a.x * b.x; acc[0][1] += a.x * b.y; acc[0][2] += a.x * b.z; acc[0][3] += a.x * b.w;
            acc[1][0] += a.y * b.x; acc[1][1] += a.y * b.y; acc[1][2] += a.y * b.z; acc[1][3] += a.y * b.w;
            acc[2][0] += a.z * b.x; acc[2][1] += a.z * b.y; acc[2][2] += a.z * b.z; acc[2][3] += a.z * b.w;
            acc[3][0] += a.w * b.x; acc[3][1] += a.w * b.y; acc[3][2] += a.w * b.z; acc[3][3] += a.w * b.w;
        }
        __syncthreads();
    }
#pragma unroll
    for (int r = 0; r < 4; ++r) {
        ushort4 wh;
        wh.x = f2bf(acc[r][0]); wh.y = f2bf(acc[r][1]);
        wh.z = f2bf(acc[r][2]); wh.w = f2bf(acc[r][3]);
        *(ushort4*)&Mh[((size_t)(z * 2048 + g0 + ty * 4 + r)) * 512 + i0 + tx * 4] = wh;
    }
}

// ---------------- K1b: hidden -> bf16 ----------------
__global__ void k_Hbf(const float* __restrict__ hidden, unsigned short* __restrict__ Hs) {
    int i = blockIdx.x * 256 + threadIdx.x;   // handles 4 floats
    float4 v = *(const float4*)&hidden[(size_t)i * 4];
    ushort4 h4;
    h4.x = f2bf(v.x); h4.y = f2bf(v.y); h4.z = f2bf(v.z); h4.w = f2bf(v.w);
    *(ushort4*)&Hs[(size_t)i * 4] = h4;
}

// ---------------- K2: conv1d(pad1,k3)+relu then dot(out_w)+sigmoid -> alphas_s[b][s] ----------------
__global__ void k_conv_alpha(const float* __restrict__ hidden, const float* __restrict__ wt,
                             const float* __restrict__ cb, const float* __restrict__ ow,
                             const float* __restrict__ ob, const float* __restrict__ mask,
                             float* __restrict__ alph_s) {
    __shared__ float hs[18 * 512];
    __shared__ float red[16][257];
    int b = blockIdx.x, s0 = blockIdx.y * 16;
    int tid = threadIdx.x;
#pragma unroll
    for (int e = 0; e < 36; ++e) {
        int idx = e * 256 + tid;
        int r = idx >> 9, i = idx & 511;
        int s = s0 + r - 1;
        hs[idx] = (s >= 0 && s < Sz) ? hidden[((size_t)b * Sz + s) * Dz + i] : 0.f;
    }
    __syncthreads();
    float acc0[16] = {}, acc1[16] = {};
    int d0 = tid, d1 = tid + 256;
    for (int i = 0; i < 512; ++i) {
        float w00 = wt[(i * 3 + 0) * 512 + d0];
        float w01 = wt[(i * 3 + 1) * 512 + d0];
        float w02 = wt[(i * 3 + 2) * 512 + d0];
        float w10 = wt[(i * 3 + 0) * 512 + d1];
        float w11 = wt[(i * 3 + 1) * 512 + d1];
        float w12 = wt[(i * 3 + 2) * 512 + d1];
        float hv[18];
#pragma unroll
        for (int r = 0; r < 18; ++r) hv[r] = hs[r * 512 + i];
#pragma unroll
        for (int j = 0; j < 16; ++j) {
            acc0[j] += hv[j] * w00 + hv[j + 1] * w01 + hv[j + 2] * w02;
            acc1[j] += hv[j] * w10 + hv[j + 1] * w11 + hv[j + 2] * w12;
        }
    }
    float cb0 = cb[d0], cb1 = cb[d1], ow0 = ow[d0], ow1 = ow[d1];
#pragma unroll
    for (int j = 0; j < 16; ++j)
        red[j][tid] = fmaxf(acc0[j] + cb0, 0.f) * ow0 + fmaxf(acc1[j] + cb1, 0.f) * ow1;
    __syncthreads();
    for (int off = 128; off >= 1; off >>= 1) {
        if (tid < off) {
#pragma unroll
            for (int j = 0; j < 16; ++j) red[j][tid] += red[j][tid + off];
        }
        __syncthreads();
    }
    if (tid < 16) {
        float v = red[tid][0] + ob[0];
        float a = sigm(v);
        a = fmaxf(a * SM1c - NT1c, 0.f);
        a *= mask[b * Sz + s0 + tid];
        alph_s[b * Sz + s0 + tid] = a;
    }
}

// ---------------- K3: CIF scalar scan (serial per batch) ----------------
__global__ void k_cif_scan(const float* __restrict__ alph_s, const float* __restrict__ mask,
                           float* __restrict__ out, float* __restrict__ sc_cur,
                           float* __restrict__ sc_res, int* __restrict__ sc_dst) {
    __shared__ float sa[16][T1];
    int tid = threadIdx.x;
    for (int idx = tid; idx < 16 * T1; idx += 256) {
        int b = idx / T1, t = idx % T1;
        float a = (t < Sz) ? alph_s[b * Sz + t] : 0.f;
        float mp = (t == 0) ? 1.f : mask[b * Sz + t - 1];
        float mc = (t < Sz) ? mask[b * Sz + t] : 0.f;
        sa[b][t] = a + (mp - mc) * TAILc;
    }
    __syncthreads();
    if (tid < 16) {
        int b = tid;
        float integ = 0.f, sum = 0.f;
        int nf = 0;
        for (int t = 0; t < T1; ++t) {
            float a = sa[b][t];
            out[ALUT_OFF + b * T1 + t] = a;
            sum += a;
            float dist = 1.f - integ;
            integ += a;
            bool fire = (integ >= THRESHc);
            float cur = fire ? dist : a;
            sc_cur[b * T1 + t] = cur;
            sc_res[b * T1 + t] = fire ? (a - cur) : 0.f;
            sc_dst[b * T1 + t] = fire ? (nf++) : -1;
            if (fire) integ -= 1.f;
        }
        out[TOK_OFF + b] = floorf(sum);
    }
}

// ---------------- K4: CIF frame accumulation / scatter ----------------
__global__ void k_cif_frames(const float* __restrict__ hidden, const float* __restrict__ sc_cur,
                             const float* __restrict__ sc_res, const int* __restrict__ sc_dst,
                             float* __restrict__ out) {
    __shared__ float cu[T1], re[T1];
    __shared__ int dsx[T1];
    int b = blockIdx.x, d = blockIdx.y * 256 + threadIdx.x;
    for (int t = threadIdx.x; t < T1; t += 256) {
        cu[t] = sc_cur[b * T1 + t];
        re[t] = sc_res[b * T1 + t];
        dsx[t] = sc_dst[b * T1 + t];
    }
    __syncthreads();
    float frame = 0.f;
    for (int t = 0; t < T1; ++t) {
        float ht = (t < Sz) ? hidden[((size_t)b * Sz + t) * Dz + d] : 0.f;
        float f = frame + cu[t] * ht;
        int dst = dsx[t];
        if (dst >= 0) {
            out[EMB_OFF + ((size_t)b * T1 + dst) * Dz + d] = f;
            frame = re[t] * ht;
        } else {
            frame = f;
        }
    }
}

// ---------------- K5: persistent cooperative BiLSTM v7 ----------------
// r5 topology (64 WGs, one direction each) + tag-embedded h exchange:
// producer stores 16B units {4 bf16 h, tag, tag} fire-and-forget (no drain,
// no prog counters, no poll). Consumer issues the gather at the END of the
// previous step (RT hidden under idot) and only VALIDATES tags at the top of
// the step, retrying on straggler staleness.
__global__ void __launch_bounds__(256, 1)
k_lstm(const unsigned short* __restrict__ Mh, const unsigned short* __restrict__ Hs,
       const float* __restrict__ whh_f, const float* __restrict__ whh_b,
       const float* __restrict__ gconst, const float* __restrict__ w2,
       u32x4* exch, float* part) {
    __shared__ unsigned short hbuf[16 * 512];   // swizzled h (batch-major rows)
    __shared__ float xch[3 * 256];

    const int wg = blockIdx.x;                  // 0..63
    const int dir = wg >> 5, slice = wg & 31;
    const int d0 = slice * GD;
    const int tid = threadIdx.x;
    const int wv = tid >> 6;                    // wave = gate (0:i 1:f 2:g 3:o)
    const int l = tid & 63;
    const int colb = l & 15;                    // batch
    const int khi = l >> 4;
    const float* whh = dir ? whh_b : whh_f;

    // one-time: W_hh bf16 fragments in registers
    bf16x8 whA[16];
    {
        const float* wr = whh + (size_t)(wv * 512 + d0 + colb) * 512 + khi * 8;
#pragma unroll
        for (int m = 0; m < 16; ++m) {
            float4 a = *(const float4*)(wr + m * 32);
            float4 b = *(const float4*)(wr + m * 32 + 4);
            union { unsigned short u[8]; bf16x8 v; } hh;
            hh.u[0] = f2bf(a.x); hh.u[1] = f2bf(a.y); hh.u[2] = f2bf(a.z); hh.u[3] = f2bf(a.w);
            hh.u[4] = f2bf(b.x); hh.u[5] = f2bf(b.y); hh.u[6] = f2bf(b.z); hh.u[7] = f2bf(b.w);
            whA[m] = hh.v;
        }
    }

    f32x4 bias;
    float w2v[4], cst[4] = {0.f, 0.f, 0.f, 0.f};
#pragma unroll
    for (int j = 0; j < 4; ++j) {
        bias[j] = gconst[dir * 2048 + wv * 512 + d0 + khi * 4 + j];
        w2v[j] = w2[dir * 512 + d0 + khi * 4 + j];
    }
    u32x4* exbase = exch + (size_t)dir * 4096;   // 2 slots x 2048 units

    auto idot = [&](int n) -> f32x4 {
        int t = dir ? (TU - 1 - n) : n;
        int s = t / 3, k = t - 3 * s;
        const unsigned short* ma = Mh + ((size_t)((dir * 3 + k) * 2048 + wv * 512 + d0 + colb)) * 512 + khi * 8;
        const unsigned short* xa = Hs + ((size_t)(colb * 512 + s)) * 512 + khi * 8;
        f32x4 a = bias;
#pragma unroll
        for (int m = 0; m < 16; ++m) {
            bf16x8 A = *(const bf16x8*)(ma + m * 32);
            bf16x8 B = *(const bf16x8*)(xa + m * 32);
            a = __builtin_amdgcn_mfma_f32_16x16x32_bf16(A, B, a, 0, 0, 0);
        }
        return a;
    };

    u32x4 gS[8];
    auto issue_gather = [&](int n) {            // gather h[n] (slot n&1, tag n+1)
        const u32x4* base = exbase + (size_t)(n & 1) * 2048 + tid * 8;
#pragma unroll
        for (int j = 0; j < 8; ++j)
            asm volatile("global_load_dwordx4 %0, %1, off sc0 sc1"
                         : "=v"(gS[j]) : "v"(base + j));
    };
    auto validate = [&](int n) {                // spin until all 8 tags fresh
        const u32x4* base = exbase + (size_t)(n & 1) * 2048 + tid * 8;
        unsigned tag = (unsigned)(n + 1);
        int it = 0;
        while (true) {
            asm volatile("s_waitcnt vmcnt(0)" ::: "memory");
            bool ok = true;
#pragma unroll
            for (int j = 0; j < 8; ++j) ok = ok && (gS[j][2] == tag);
            if (__ballot(!ok) == 0ull) break;
            if (++it > (1 << 13)) break;
            __builtin_amdgcn_s_sleep(1);
#pragma unroll
            for (int j = 0; j < 8; ++j)
                asm volatile("global_load_dwordx4 %0, %1, off sc0 sc1"
                             : "=v"(gS[j]) : "v"(base + j));
        }
    };
    auto unpack = [&]() {                       // 8B payload -> swizzled LDS
#pragma unroll
        for (int j = 0; j < 8; ++j) {
            int u = tid * 8 + j;
            int batch = u & 15;
            int gq = u >> 4;                    // 4-dim (8B) granule 0..127
            int sw = (((gq >> 1) ^ (batch & 7)) << 3) + ((gq & 1) << 2);
            u64 q = (u64)gS[j][0] | ((u64)gS[j][1] << 32);
            *(u64*)&hbuf[batch * 512 + sw] = q;
        }
    };
    auto hhdot = [&](f32x4 acc) -> f32x4 {
#pragma unroll
        for (int m = 0; m < 16; ++m) {
            bf16x8 B = *(const bf16x8*)&hbuf[colb * 512 + (((m * 4 + khi) ^ (colb & 7)) << 3)];
            acc = __builtin_amdgcn_mfma_f32_16x16x32_bf16(whA[m], B, acc, 0, 0, 0);
        }
        return acc;
    };

    f32x4 accA = idot(0);

    for (int n = 0; n < TU; ++n) {
        int t = dir ? (TU - 1 - n) : n;
        if (n > 0) {
            validate(n - 1);                    // gS issued at end of prev iteration
            unpack();
            __syncthreads();
            accA = hhdot(accA);
        }
        // ---- cell phase: store h FIRST (critical), us-partial after ----
        if (wv != 0) {
#pragma unroll
            for (int j = 0; j < 4; ++j)
                xch[(wv - 1) * 256 + (khi * 4 + j) * 16 + colb] = accA[j];
        }
        __syncthreads();
        if (wv == 0) {
            unsigned short h4[4];
            float hr[4];
#pragma unroll
            for (int j = 0; j < 4; ++j) {
                int rr = khi * 4 + j;
                float gi = accA[j];
                float gf = xch[0 * 256 + rr * 16 + colb];
                float gg = xch[1 * 256 + rr * 16 + colb];
                float go = xch[2 * 256 + rr * 16 + colb];
                float c2 = fsigm(gf) * cst[j] + fsigm(gi) * ftanh(gg);
                cst[j] = c2;
                float h = fsigm(go) * ftanh(c2);
                h4[j] = f2bf(h);
                hr[j] = h;
            }
            unsigned lo = (unsigned)h4[0] | ((unsigned)h4[1] << 16);
            unsigned hi = (unsigned)h4[2] | ((unsigned)h4[3] << 16);
            unsigned tg = (unsigned)(n + 1);
            u32x4 outv = { lo, hi, tg, tg };
            u32x4* dst = exbase + (size_t)(n & 1) * 2048 + slice * 64 + l;
            asm volatile("global_store_dwordx4 %0, %1, off sc0 sc1"
                         :: "v"(dst), "v"(outv) : "memory");
            // us-partial (off the exchange critical path)
            float p = hr[0] * w2v[0] + hr[1] * w2v[1] + hr[2] * w2v[2] + hr[3] * w2v[3];
            p += __shfl_xor(p, 16);
            p += __shfl_xor(p, 32);
            if (l < 16)
                part[((size_t)((dir * 32 + slice) * 16) + l) * TU + t] = p;
        }
        __syncthreads();                        // gathers issue after own store issued
        if (n + 1 < TU) {
            issue_gather(n);                    // RT hides under idot(n+1)
            accA = idot(n + 1);
        }
    }
}

// ---------------- K6: reduce us partials, activation, pre-norm ----------------
__global__ void k_us_reduce(const float* __restrict__ part, const float* __restrict__ ob2,
                            const float* __restrict__ mask, float* __restrict__ usA,
                            float* __restrict__ csum) {
    int b = blockIdx.x, ch = blockIdx.y;
    int t = ch * 256 + threadIdx.x;
    float s = 0.f;
#pragma unroll 8
    for (int p = 0; p < 64; ++p) s += part[((size_t)p * Bz + b) * TU + t];
    float u = sigm(s + ob2[0]);
    float ua = fmaxf(u * SM2c - NT2c, 0.f) * mask[b * Sz + t / 3];
    usA[b * TU + t] = ua;
    __shared__ float red[256];
    red[threadIdx.x] = ua;
    __syncthreads();
    for (int off = 128; off >= 1; off >>= 1) {
        if (threadIdx.x < off) red[threadIdx.x] += red[threadIdx.x + off];
        __syncthreads();
    }
    if (threadIdx.x == 0) csum[b * 6 + ch] = red[0];
}

// ---------------- K7: normalize + peak scan (serial per batch) ----------------
__global__ void k_us_scan(const float* __restrict__ usA, const float* __restrict__ csum,
                          float* __restrict__ out) {
    __shared__ float ubuf[TU];
    int b = blockIdx.x;
    for (int t = threadIdx.x; t < TU; t += 64) ubuf[t] = usA[b * TU + t];
    __syncthreads();
    if (threadIdx.x == 0) {
        float tot = 0.f;
        for (int c = 0; c < 6; ++c) tot += csum[b * 6 + c];
        float scale = out[TOK_OFF + b] / tot;
        float integ = 0.f;
        const float th = THRESHc - 0.0001f;
        for (int t = 0; t < TU; ++t) {
            float ua = ubuf[t] * scale;
            out[USA_OFF + b * TU + t] = ua;
            integ += ua;
            out[USP_OFF + b * TU + t] = integ;
            if (integ >= th) integ -= th;
        }
    }
}

// ---------------- host ----------------
extern "C" void kernel_launch(void* const* d_in, const int* in_sizes, int n_in,
                              void* d_out, int out_size, void* d_ws, size_t ws_size,
                              hipStream_t stream) {
    const float* hidden = (const float*)d_in[0];
    const float* mask   = (const float*)d_in[1];
    const float* conv_w = (const float*)d_in[2];
    const float* conv_b = (const float*)d_in[3];
    const float* out_w  = (const float*)d_in[4];
    const float* out_b  = (const float*)d_in[5];
    const float* up_w   = (const float*)d_in[6];
    const float* up_b   = (const float*)d_in[7];
    const float* w_ih_f = (const float*)d_in[8];
    const float* w_hh_f = (const float*)d_in[9];
    const float* b_ih_f = (const float*)d_in[10];
    const float* b_hh_f = (const float*)d_in[11];
    const float* w_ih_b = (const float*)d_in[12];
    const float* w_hh_b = (const float*)d_in[13];
    const float* b_ih_b = (const float*)d_in[14];
    const float* b_hh_b = (const float*)d_in[15];
    const float* out2_w = (const float*)d_in[16];
    const float* out2_b = (const float*)d_in[17];
    float* out = (float*)d_out;
    float* ws = (float*)d_ws;

    // workspace layout (float slots), total ~8.48M floats = 33.9 MB
    float* wt     = ws + 0;              // 786,432
    float* upt    = ws + 786432;         // 786,432
    float* part   = ws + 1572864;        // 1,572,864
    float* gconst = ws + 3145728;        // 4096
    float* alph_s = ws + 3149824;        // 8192
    float* sc_cur = ws + 3158016;        // 8208
    float* sc_res = ws + 3166224;        // 8208
    int*   sc_dst = (int*)(ws + 3174432);            // 8208
    float* usA    = ws + 3182640;        // 24576
    float* csum   = ws + 3207216;        // 96
    unsigned short* Mh = (unsigned short*)(ws + 3207312);   // 6,291,456 shorts
    unsigned short* Hs = (unsigned short*)(ws + 6353040);   // 4,194,304 shorts
    u32x4* exch   = (u32x4*)(ws + 8450192);          // 8192 units x 16 B = 128 KB

    hipMemsetAsync(out, 0, (size_t)Bz * T1 * Dz * sizeof(float), stream);   // embeds region
    hipMemsetAsync(exch, 0, 8192 * 16, stream);      // tags -> 0 (fresh each launch/replay)

    k_transpose_convw<<<dim3(8, 24), 256, 0, stream>>>(conv_w, wt);
    k_transpose_upw<<<dim3(8, 24), 256, 0, stream>>>(up_w, upt);
    k_gconst<<<16, 256, 0, stream>>>(w_ih_f, b_ih_f, b_hh_f, w_ih_b, b_ih_b, b_hh_b, up_b, gconst);
    k_M<<<dim3(8, 32, 6), 256, 0, stream>>>(w_ih_f, w_ih_b, upt, Mh);
    k_Hbf<<<4096, 256, 0, stream>>>(hidden, Hs);
    k_conv_alpha<<<dim3(16, 32), 256, 0, stream>>>(hidden, wt, conv_b, out_w, out_b, mask, alph_s);
    k_cif_scan<<<1, 256, 0, stream>>>(alph_s, mask, out, sc_cur, sc_res, sc_dst);
    k_cif_frames<<<dim3(16, 2), 256, 0, stream>>>(hidden, sc_cur, sc_res, sc_dst, out);

    {
        void* args[] = { (void*)&Mh, (void*)&Hs, (void*)&w_hh_f, (void*)&w_hh_b,
                         (void*)&gconst, (void*)&out2_w, (void*)&exch, (void*)&part };
        hipLaunchCooperativeKernel(reinterpret_cast<void*>(&k_lstm), dim3(64), dim3(256),
                                   args, 0, stream);
    }

    k_us_reduce<<<dim3(16, 6), 256, 0, stream>>>(part, out2_b, mask, usA, csum);
    k_us_scan<<<16, 64, 0, stream>>>(usA, csum, out);
}

// Round 8
// 12875.996 us; speedup vs baseline: 1.4376x; 1.0511x over previous
//
#include <hip/hip_runtime.h>
#include <math.h>

// ---------------- problem constants ----------------
constexpr int Bz = 16;
constexpr int Sz = 512;
constexpr int Dz = 512;
constexpr int T1 = Sz + 1;     // 513
constexpr int TU = Sz * 3;     // 1536
constexpr float THRESHc = 1.0f;
constexpr float SM1c = 1.0f, NT1c = 0.0f;
constexpr float TAILc = 0.45f;
constexpr float SM2c = 0.25f, NT2c = 0.01f;

// LSTM persistent-kernel geometry: 64 WGs (32 per direction), 16 h-dims each
constexpr int GD = 16;

// output layout (floats)
constexpr int EMB_OFF = 0;
constexpr int TOK_OFF = Bz * T1 * Dz;            // 4202496
constexpr int ALUT_OFF = TOK_OFF + Bz;           // 4202512
constexpr int USA_OFF = ALUT_OFF + Bz * T1;      // 4210720
constexpr int USP_OFF = USA_OFF + Bz * TU;       // 4235296

typedef short bf16x8 __attribute__((ext_vector_type(8)));
typedef float f32x4 __attribute__((ext_vector_type(4)));
typedef unsigned u32x4 __attribute__((ext_vector_type(4)));
typedef unsigned long long u64;

__device__ __forceinline__ float sigm(float x) { return 1.0f / (1.0f + expf(-x)); }
__device__ __forceinline__ float fsigm(float x) { return 1.0f / (1.0f + __expf(-x)); }
__device__ __forceinline__ float ftanh(float x) {
    float e = __expf(2.0f * x);
    return 1.0f - 2.0f / (e + 1.0f);
}
__device__ __forceinline__ unsigned short f2bf(float f) {
    unsigned u = __float_as_uint(f);
    return (unsigned short)((u + 0x7fffu + ((u >> 16) & 1u)) >> 16);
}

// ---------------- K0a: transpose conv_w -> wt[(i*3+k)*512 + d] ----------------
__global__ void k_transpose_convw(const float* __restrict__ cw, float* __restrict__ wt) {
    __shared__ float tile[64][65];
    int dt = blockIdx.x * 64, ct = blockIdx.y * 64;
    int tx = threadIdx.x & 63, ty = threadIdx.x >> 6;
    for (int r = ty; r < 64; r += 4)
        tile[r][tx] = cw[(dt + r) * 1536 + ct + tx];
    __syncthreads();
    for (int r = ty; r < 64; r += 4)
        wt[(ct + r) * 512 + dt + tx] = tile[tx][r];
}

// ---------------- K0b: transpose up_w -> upt[(k*512+o)*512 + i] ----------------
__global__ void k_transpose_upw(const float* __restrict__ uw, float* __restrict__ upt) {
    __shared__ float tile[64][65];
    int it = blockIdx.x * 64, ct = blockIdx.y * 64;
    int tx = threadIdx.x & 63, ty = threadIdx.x >> 6;
    for (int r = ty; r < 64; r += 4)
        tile[r][tx] = uw[(it + r) * 1536 + ct + tx];
    __syncthreads();
    for (int r = ty; r < 64; r += 4) {
        int c = ct + r;
        int k = c % 3, o = c / 3;
        upt[(k * 512 + o) * 512 + it + tx] = tile[tx][r];
    }
}

// ---------------- K0c: gconst[dir*2048+g] = b_ih+b_hh+sum_o up_b[o]*w_ih[g][o] ----------------
__global__ void k_gconst(const float* __restrict__ wih_f, const float* __restrict__ bih_f,
                         const float* __restrict__ bhh_f, const float* __restrict__ wih_b,
                         const float* __restrict__ bih_b, const float* __restrict__ bhh_b,
                         const float* __restrict__ upb, float* __restrict__ gconst) {
    int g = blockIdx.x * 256 + threadIdx.x;   // 0..4095
    int dir = g >> 11, gg = g & 2047;
    const float* wih = dir ? wih_b : wih_f;
    const float* bi = dir ? bih_b : bih_f;
    const float* bh = dir ? bhh_b : bhh_f;
    float s = bi[gg] + bh[gg];
    const float4* w4 = (const float4*)(wih + (size_t)gg * 512);
    const float4* u4 = (const float4*)upb;
    for (int o = 0; o < 128; ++o) {
        float4 w = w4[o], u = u4[o];
        s += w.x * u.x + w.y * u.y + w.z * u.z + w.w * u.w;
    }
    gconst[g] = s;
}

// ---------------- K1: M[(dir*3+k)*2048+g][i] = sum_o wih[g][o]*upt[k][o][i], bf16 ----------------
__global__ void k_M(const float* __restrict__ wih_f, const float* __restrict__ wih_b,
                    const float* __restrict__ upt, unsigned short* __restrict__ Mh) {
    __shared__ float As[32][68];
    __shared__ float Bs[32][68];
    int z = blockIdx.z;
    int dir = z / 3, k = z % 3;
    const float* A = dir ? wih_b : wih_f;
    const float* Bt = upt + (size_t)k * 262144;
    int g0 = blockIdx.y * 64, i0 = blockIdx.x * 64;
    int tid = threadIdx.x;
    int tx = tid & 15, ty = tid >> 4;
    float acc[4][4] = {};
    for (int k0 = 0; k0 < 512; k0 += 32) {
#pragma unroll
        for (int e = 0; e < 8; ++e) {
            int idx = e * 256 + tid;
            int ko = idx & 31, gl = idx >> 5;
            As[ko][gl] = A[(size_t)(g0 + gl) * 512 + k0 + ko];
        }
#pragma unroll
        for (int e = 0; e < 8; ++e) {
            int idx = e * 256 + tid;
            int il = idx & 63, ko = idx >> 6;
            Bs[ko][il] = Bt[(size_t)(k0 + ko) * 512 + i0 + il];
        }
        __syncthreads();
#pragma unroll
        for (int ko = 0; ko < 32; ++ko) {
            float4 a = *(const float4*)&As[ko][ty * 4];
            float4 b = *(const float4*)&Bs[ko][tx * 4];
            acc[0][0] += a.x * b.x; acc[0][1] += a.x * b.y; acc[0][2] += a.x * b.z; acc[0][3] += a.x * b.w;
            acc[1][0] += a.y * b.x; acc[1][1] += a.y * b.y; acc[1][2] += a.y * b.z; acc[1][3] += a.y * b.w;
            acc[2][0] += a.z * b.x; acc[2][1] += a.z * b.y; acc[2][2] += a.z * b.z; acc[2][3] += a.z * b.w;
            acc[3][0] += a.w * b.x; acc[3][1] += a.w * b.y; acc[3][2] += a.w * b.z; acc[3][3] += a.w * b.w;
        }
        __syncthreads();
    }
#pragma unroll
    for (int r = 0; r < 4; ++r) {
        ushort4 wh;
        wh.x = f2bf(acc[r][0]); wh.y = f2bf(acc[r][1]);
        wh.z = f2bf(acc[r][2]); wh.w = f2bf(acc[r][3]);
        *(ushort4*)&Mh[((size_t)(z * 2048 + g0 + ty * 4 + r)) * 512 + i0 + tx * 4] = wh;
    }
}

// ---------------- K1b: hidden -> bf16 ----------------
__global__ void k_Hbf(const float* __restrict__ hidden, unsigned short* __restrict__ Hs) {
    int i = blockIdx.x * 256 + threadIdx.x;   // handles 4 floats
    float4 v = *(const float4*)&hidden[(size_t)i * 4];
    ushort4 h4;
    h4.x = f2bf(v.x); h4.y = f2bf(v.y); h4.z = f2bf(v.z); h4.w = f2bf(v.w);
    *(ushort4*)&Hs[(size_t)i * 4] = h4;
}

// ---------------- K2: conv1d(pad1,k3)+relu then dot(out_w)+sigmoid -> alphas_s[b][s] ----------------
__global__ void k_conv_alpha(const float* __restrict__ hidden, const float* __restrict__ wt,
                             const float* __restrict__ cb, const float* __restrict__ ow,
                             const float* __restrict__ ob, const float* __restrict__ mask,
                             float* __restrict__ alph_s) {
    __shared__ float hs[18 * 512];
    __shared__ float red[16][257];
    int b = blockIdx.x, s0 = blockIdx.y * 16;
    int tid = threadIdx.x;
#pragma unroll
    for (int e = 0; e < 36; ++e) {
        int idx = e * 256 + tid;
        int r = idx >> 9, i = idx & 511;
        int s = s0 + r - 1;
        hs[idx] = (s >= 0 && s < Sz) ? hidden[((size_t)b * Sz + s) * Dz + i] : 0.f;
    }
    __syncthreads();
    float acc0[16] = {}, acc1[16] = {};
    int d0 = tid, d1 = tid + 256;
    for (int i = 0; i < 512; ++i) {
        float w00 = wt[(i * 3 + 0) * 512 + d0];
        float w01 = wt[(i * 3 + 1) * 512 + d0];
        float w02 = wt[(i * 3 + 2) * 512 + d0];
        float w10 = wt[(i * 3 + 0) * 512 + d1];
        float w11 = wt[(i * 3 + 1) * 512 + d1];
        float w12 = wt[(i * 3 + 2) * 512 + d1];
        float hv[18];
#pragma unroll
        for (int r = 0; r < 18; ++r) hv[r] = hs[r * 512 + i];
#pragma unroll
        for (int j = 0; j < 16; ++j) {
            acc0[j] += hv[j] * w00 + hv[j + 1] * w01 + hv[j + 2] * w02;
            acc1[j] += hv[j] * w10 + hv[j + 1] * w11 + hv[j + 2] * w12;
        }
    }
    float cb0 = cb[d0], cb1 = cb[d1], ow0 = ow[d0], ow1 = ow[d1];
#pragma unroll
    for (int j = 0; j < 16; ++j)
        red[j][tid] = fmaxf(acc0[j] + cb0, 0.f) * ow0 + fmaxf(acc1[j] + cb1, 0.f) * ow1;
    __syncthreads();
    for (int off = 128; off >= 1; off >>= 1) {
        if (tid < off) {
#pragma unroll
            for (int j = 0; j < 16; ++j) red[j][tid] += red[j][tid + off];
        }
        __syncthreads();
    }
    if (tid < 16) {
        float v = red[tid][0] + ob[0];
        float a = sigm(v);
        a = fmaxf(a * SM1c - NT1c, 0.f);
        a *= mask[b * Sz + s0 + tid];
        alph_s[b * Sz + s0 + tid] = a;
    }
}

// ---------------- K3: CIF scalar scan (serial per batch) ----------------
__global__ void k_cif_scan(const float* __restrict__ alph_s, const float* __restrict__ mask,
                           float* __restrict__ out, float* __restrict__ sc_cur,
                           float* __restrict__ sc_res, int* __restrict__ sc_dst) {
    __shared__ float sa[16][T1];
    int tid = threadIdx.x;
    for (int idx = tid; idx < 16 * T1; idx += 256) {
        int b = idx / T1, t = idx % T1;
        float a = (t < Sz) ? alph_s[b * Sz + t] : 0.f;
        float mp = (t == 0) ? 1.f : mask[b * Sz + t - 1];
        float mc = (t < Sz) ? mask[b * Sz + t] : 0.f;
        sa[b][t] = a + (mp - mc) * TAILc;
    }
    __syncthreads();
    if (tid < 16) {
        int b = tid;
        float integ = 0.f, sum = 0.f;
        int nf = 0;
        for (int t = 0; t < T1; ++t) {
            float a = sa[b][t];
            out[ALUT_OFF + b * T1 + t] = a;
            sum += a;
            float dist = 1.f - integ;
            integ += a;
            bool fire = (integ >= THRESHc);
            float cur = fire ? dist : a;
            sc_cur[b * T1 + t] = cur;
            sc_res[b * T1 + t] = fire ? (a - cur) : 0.f;
            sc_dst[b * T1 + t] = fire ? (nf++) : -1;
            if (fire) integ -= 1.f;
        }
        out[TOK_OFF + b] = floorf(sum);
    }
}

// ---------------- K4: CIF frame accumulation / scatter ----------------
__global__ void k_cif_frames(const float* __restrict__ hidden, const float* __restrict__ sc_cur,
                             const float* __restrict__ sc_res, const int* __restrict__ sc_dst,
                             float* __restrict__ out) {
    __shared__ float cu[T1], re[T1];
    __shared__ int dsx[T1];
    int b = blockIdx.x, d = blockIdx.y * 256 + threadIdx.x;
    for (int t = threadIdx.x; t < T1; t += 256) {
        cu[t] = sc_cur[b * T1 + t];
        re[t] = sc_res[b * T1 + t];
        dsx[t] = sc_dst[b * T1 + t];
    }
    __syncthreads();
    float frame = 0.f;
    for (int t = 0; t < T1; ++t) {
        float ht = (t < Sz) ? hidden[((size_t)b * Sz + t) * Dz + d] : 0.f;
        float f = frame + cu[t] * ht;
        int dst = dsx[t];
        if (dst >= 0) {
            out[EMB_OFF + ((size_t)b * T1 + dst) * Dz + d] = f;
            frame = re[t] * ht;
        } else {
            frame = f;
        }
    }
}

// ---------------- K5: persistent cooperative BiLSTM v8 ----------------
// r5 structure (poll-small-then-gather-once, 64 WGs) with:
//  - tagged 16B h-units (no producer vmcnt drain before prog)
//  - tag validation after the single gather (retry rare)
//  - cell distributed over all 4 waves (1 cell/lane)
//  - padded gate-exchange LDS (no 4-way conflicts)
__global__ void __launch_bounds__(256, 1)
k_lstm(const unsigned short* __restrict__ Mh, const unsigned short* __restrict__ Hs,
       const float* __restrict__ whh_f, const float* __restrict__ whh_b,
       const float* __restrict__ gconst, const float* __restrict__ w2,
       u32x4* exch, float* part, int* prog) {
    __shared__ unsigned short hbuf[16 * 512];   // swizzled h (batch-major rows)
    __shared__ float xch[4 * 16 * 17];          // [gate][dim][batch], padded 17
    __shared__ float pbuf[64];

    const int wg = blockIdx.x;                  // 0..63
    const int dir = wg >> 5, slice = wg & 31;
    const int d0 = slice * GD;
    const int tid = threadIdx.x;
    const int wv = tid >> 6;                    // wave = gate (0:i 1:f 2:g 3:o)
    const int l = tid & 63;
    const int colb = l & 15;                    // batch
    const int khi = l >> 4;
    const float* whh = dir ? whh_b : whh_f;

    // one-time: W_hh bf16 fragments in registers
    bf16x8 whA[16];
    {
        const float* wr = whh + (size_t)(wv * 512 + d0 + colb) * 512 + khi * 8;
#pragma unroll
        for (int m = 0; m < 16; ++m) {
            float4 a = *(const float4*)(wr + m * 32);
            float4 b = *(const float4*)(wr + m * 32 + 4);
            union { unsigned short u[8]; bf16x8 v; } hh;
            hh.u[0] = f2bf(a.x); hh.u[1] = f2bf(a.y); hh.u[2] = f2bf(a.z); hh.u[3] = f2bf(a.w);
            hh.u[4] = f2bf(b.x); hh.u[5] = f2bf(b.y); hh.u[6] = f2bf(b.z); hh.u[7] = f2bf(b.w);
            whA[m] = hh.v;
        }
    }

    f32x4 bias;
#pragma unroll
    for (int j = 0; j < 4; ++j)
        bias[j] = gconst[dir * 2048 + wv * 512 + d0 + khi * 4 + j];
    const int dloc = wv * 4 + khi;              // cell dim owned by this lane
    const float w2c = w2[dir * 512 + d0 + dloc];
    float cstv = 0.f;

    int* myprog = prog + (dir * 32 + slice) * 16;
    const int* pollp = prog + (dir * 32 + (l & 31)) * 16;
    u32x4* exbase = exch + (size_t)dir * 4096;  // 2 slots x 2048 units

    auto idot = [&](int n) -> f32x4 {
        int t = dir ? (TU - 1 - n) : n;
        int s = t / 3, k = t - 3 * s;
        const unsigned short* ma = Mh + ((size_t)((dir * 3 + k) * 2048 + wv * 512 + d0 + colb)) * 512 + khi * 8;
        const unsigned short* xa = Hs + ((size_t)(colb * 512 + s)) * 512 + khi * 8;
        f32x4 a = bias;
#pragma unroll
        for (int m = 0; m < 16; ++m) {
            bf16x8 A = *(const bf16x8*)(ma + m * 32);
            bf16x8 B = *(const bf16x8*)(xa + m * 32);
            a = __builtin_amdgcn_mfma_f32_16x16x32_bf16(A, B, a, 0, 0, 0);
        }
        return a;
    };

    f32x4 accA = idot(0);

    for (int n = 0; n < TU; ++n) {
        int t = dir ? (TU - 1 - n) : n;
        if (n > 0) {
            // ---- 1. poll prog (small loads) until all 32 producers done step n-1 ----
            {
                int it = 0;
                while (true) {
                    int v;
                    asm volatile("global_load_dword %0, %1, off sc0 sc1\n\ts_waitcnt vmcnt(0)"
                                 : "=v"(v) : "v"(pollp));
                    if (__ballot(v >= n) == ~0ull) break;
                    if (++it > (1 << 15)) break;
                    __builtin_amdgcn_s_sleep(1);
                }
            }
            // ---- 2. single gather of tagged h units (32 KB coalesced) ----
            const u32x4* base = exbase + (size_t)((n - 1) & 1) * 2048 + tid * 8;
            u32x4 gS[8];
#pragma unroll
            for (int j = 0; j < 8; ++j)
                asm volatile("global_load_dwordx4 %0, %1, off sc0 sc1"
                             : "=v"(gS[j]) : "v"(base + j));
            // ---- 3. validate tags (retry rare: prog outran units in MALL) ----
            {
                unsigned tag = (unsigned)n;
                int it = 0;
                while (true) {
                    asm volatile("s_waitcnt vmcnt(0)" ::: "memory");
                    bool ok = true;
#pragma unroll
                    for (int j = 0; j < 8; ++j) ok = ok && (gS[j][2] == tag);
                    if (__ballot(!ok) == 0ull) break;
                    if (++it > (1 << 13)) break;
                    __builtin_amdgcn_s_sleep(1);
#pragma unroll
                    for (int j = 0; j < 8; ++j)
                        asm volatile("global_load_dwordx4 %0, %1, off sc0 sc1"
                                     : "=v"(gS[j]) : "v"(base + j));
                }
            }
            // ---- 4. unpack payloads to swizzled LDS ----
#pragma unroll
            for (int j = 0; j < 8; ++j) {
                int u = tid * 8 + j;
                int batch = u & 15;
                int gq = u >> 4;                // 4-dim granule 0..127
                int sw = (((gq >> 1) ^ (batch & 7)) << 3) + ((gq & 1) << 2);
                u64 q = (u64)gS[j][0] | ((u64)gS[j][1] << 32);
                *(u64*)&hbuf[batch * 512 + sw] = q;
            }
            __syncthreads();
#pragma unroll
            for (int m = 0; m < 16; ++m) {
                bf16x8 B = *(const bf16x8*)&hbuf[colb * 512 + (((m * 4 + khi) ^ (colb & 7)) << 3)];
                accA = __builtin_amdgcn_mfma_f32_16x16x32_bf16(whA[m], B, accA, 0, 0, 0);
            }
        }
        // ---- gate exchange: ALL waves write their gate tile (padded rows) ----
#pragma unroll
        for (int j = 0; j < 4; ++j)
            xch[wv * 272 + (khi * 4 + j) * 17 + colb] = accA[j];
        __syncthreads();
        // ---- cell: 1 (dim,batch) per lane across all 4 waves ----
        {
            float gi = xch[0 * 272 + dloc * 17 + colb];
            float gf = xch[1 * 272 + dloc * 17 + colb];
            float gg = xch[2 * 272 + dloc * 17 + colb];
            float go = xch[3 * 272 + dloc * 17 + colb];
            float c2 = fsigm(gf) * cstv + fsigm(gi) * ftanh(gg);
            cstv = c2;
            float h = fsigm(go) * ftanh(c2);
            // pack 4 dims (lanes khi=0..3, same colb) into one tagged 16B unit
            unsigned hb = (unsigned)f2bf(h);
            unsigned lo = hb | (__shfl_xor(hb, 16) << 16);   // dims (wv*4+0, +1) at khi even
            unsigned hi = __shfl_xor(lo, 32);                // dims (wv*4+2, +3) at khi 0
            if (khi == 0) {
                unsigned tg = (unsigned)(n + 1);
                u32x4 outv = { lo, hi, tg, tg };
                u32x4* dst = exbase + (size_t)(n & 1) * 2048 + (slice * 64 + wv * 16 + colb);
                asm volatile("global_store_dwordx4 %0, %1, off sc0 sc1"
                             :: "v"(dst), "v"(outv) : "memory");
            }
            // us-partial: sum over this wave's 4 dims
            float p = h * w2c;
            p += __shfl_xor(p, 16);
            p += __shfl_xor(p, 32);
            if (khi == 0) pbuf[wv * 16 + colb] = p;
        }
        __syncthreads();
        if (wv == 0 && l < 16) {
            float ps = pbuf[l] + pbuf[16 + l] + pbuf[32 + l] + pbuf[48 + l];
            part[((size_t)((dir * 32 + slice) * 16) + l) * TU + t] = ps;
        }
        if (tid == 0) {
            int nv = n + 1;
            asm volatile("global_store_dword %0, %1, off sc0 sc1"
                         :: "v"(myprog), "v"(nv) : "memory");
        }
        // next-step input dot: off the waited path, overlaps others' progress
        if (n + 1 < TU) accA = idot(n + 1);
    }
}

// ---------------- K6: reduce us partials, activation, pre-norm ----------------
__global__ void k_us_reduce(const float* __restrict__ part, const float* __restrict__ ob2,
                            const float* __restrict__ mask, float* __restrict__ usA,
                            float* __restrict__ csum) {
    int b = blockIdx.x, ch = blockIdx.y;
    int t = ch * 256 + threadIdx.x;
    float s = 0.f;
#pragma unroll 8
    for (int p = 0; p < 64; ++p) s += part[((size_t)p * Bz + b) * TU + t];
    float u = sigm(s + ob2[0]);
    float ua = fmaxf(u * SM2c - NT2c, 0.f) * mask[b * Sz + t / 3];
    usA[b * TU + t] = ua;
    __shared__ float red[256];
    red[threadIdx.x] = ua;
    __syncthreads();
    for (int off = 128; off >= 1; off >>= 1) {
        if (threadIdx.x < off) red[threadIdx.x] += red[threadIdx.x + off];
        __syncthreads();
    }
    if (threadIdx.x == 0) csum[b * 6 + ch] = red[0];
}

// ---------------- K7: normalize + peak scan (serial per batch) ----------------
__global__ void k_us_scan(const float* __restrict__ usA, const float* __restrict__ csum,
                          float* __restrict__ out) {
    __shared__ float ubuf[TU];
    int b = blockIdx.x;
    for (int t = threadIdx.x; t < TU; t += 64) ubuf[t] = usA[b * TU + t];
    __syncthreads();
    if (threadIdx.x == 0) {
        float tot = 0.f;
        for (int c = 0; c < 6; ++c) tot += csum[b * 6 + c];
        float scale = out[TOK_OFF + b] / tot;
        float integ = 0.f;
        const float th = THRESHc - 0.0001f;
        for (int t = 0; t < TU; ++t) {
            float ua = ubuf[t] * scale;
            out[USA_OFF + b * TU + t] = ua;
            integ += ua;
            out[USP_OFF + b * TU + t] = integ;
            if (integ >= th) integ -= th;
        }
    }
}

// ---------------- host ----------------
extern "C" void kernel_launch(void* const* d_in, const int* in_sizes, int n_in,
                              void* d_out, int out_size, void* d_ws, size_t ws_size,
                              hipStream_t stream) {
    const float* hidden = (const float*)d_in[0];
    const float* mask   = (const float*)d_in[1];
    const float* conv_w = (const float*)d_in[2];
    const float* conv_b = (const float*)d_in[3];
    const float* out_w  = (const float*)d_in[4];
    const float* out_b  = (const float*)d_in[5];
    const float* up_w   = (const float*)d_in[6];
    const float* up_b   = (const float*)d_in[7];
    const float* w_ih_f = (const float*)d_in[8];
    const float* w_hh_f = (const float*)d_in[9];
    const float* b_ih_f = (const float*)d_in[10];
    const float* b_hh_f = (const float*)d_in[11];
    const float* w_ih_b = (const float*)d_in[12];
    const float* w_hh_b = (const float*)d_in[13];
    const float* b_ih_b = (const float*)d_in[14];
    const float* b_hh_b = (const float*)d_in[15];
    const float* out2_w = (const float*)d_in[16];
    const float* out2_b = (const float*)d_in[17];
    float* out = (float*)d_out;
    float* ws = (float*)d_ws;

    // workspace layout (float slots), total ~8.49M floats = 34.0 MB
    float* wt     = ws + 0;              // 786,432
    float* upt    = ws + 786432;         // 786,432
    float* part   = ws + 1572864;        // 1,572,864
    float* gconst = ws + 3145728;        // 4096
    float* alph_s = ws + 3149824;        // 8192
    float* sc_cur = ws + 3158016;        // 8208
    float* sc_res = ws + 3166224;        // 8208
    int*   sc_dst = (int*)(ws + 3174432);            // 8208
    float* usA    = ws + 3182640;        // 24576
    float* csum   = ws + 3207216;        // 96
    unsigned short* Mh = (unsigned short*)(ws + 3207312);   // 6,291,456 shorts
    unsigned short* Hs = (unsigned short*)(ws + 6353040);   // 4,194,304 shorts
    u32x4* exch   = (u32x4*)(ws + 8450192);          // 8192 units x 16 B = 128 KB
    int*   prog   = (int*)(ws + 8482960);            // 1024 ints (64 counters, 64B stride)

    hipMemsetAsync(out, 0, (size_t)Bz * T1 * Dz * sizeof(float), stream);   // embeds region
    hipMemsetAsync(exch, 0, 8192 * 16, stream);      // tags -> 0 each launch/replay
    hipMemsetAsync(prog, 0, 1024 * sizeof(int), stream);

    k_transpose_convw<<<dim3(8, 24), 256, 0, stream>>>(conv_w, wt);
    k_transpose_upw<<<dim3(8, 24), 256, 0, stream>>>(up_w, upt);
    k_gconst<<<16, 256, 0, stream>>>(w_ih_f, b_ih_f, b_hh_f, w_ih_b, b_ih_b, b_hh_b, up_b, gconst);
    k_M<<<dim3(8, 32, 6), 256, 0, stream>>>(w_ih_f, w_ih_b, upt, Mh);
    k_Hbf<<<4096, 256, 0, stream>>>(hidden, Hs);
    k_conv_alpha<<<dim3(16, 32), 256, 0, stream>>>(hidden, wt, conv_b, out_w, out_b, mask, alph_s);
    k_cif_scan<<<1, 256, 0, stream>>>(alph_s, mask, out, sc_cur, sc_res, sc_dst);
    k_cif_frames<<<dim3(16, 2), 256, 0, stream>>>(hidden, sc_cur, sc_res, sc_dst, out);

    {
        void* args[] = { (void*)&Mh, (void*)&Hs, (void*)&w_hh_f, (void*)&w_hh_b,
                         (void*)&gconst, (void*)&out2_w, (void*)&exch, (void*)&part,
                         (void*)&prog };
        hipLaunchCooperativeKernel(reinterpret_cast<void*>(&k_lstm), dim3(64), dim3(256),
                                   args, 0, stream);
    }

    k_us_reduce<<<dim3(16, 6), 256, 0, stream>>>(part, out2_b, mask, usA, csum);
    k_us_scan<<<16, 64, 0, stream>>>(usA, csum, out);
}

// Round 9
// 12669.930 us; speedup vs baseline: 1.4609x; 1.0163x over previous
//
#include <hip/hip_runtime.h>
#include <math.h>

// ---------------- problem constants ----------------
constexpr int Bz = 16;
constexpr int Sz = 512;
constexpr int Dz = 512;
constexpr int T1 = Sz + 1;     // 513
constexpr int TU = Sz * 3;     // 1536
constexpr float THRESHc = 1.0f;
constexpr float SM1c = 1.0f, NT1c = 0.0f;
constexpr float TAILc = 0.45f;
constexpr float SM2c = 0.25f, NT2c = 0.01f;

// LSTM persistent-kernel geometry: 32 WGs total (16 per direction), 32 h-dims each
constexpr int SLD = 16;        // slices per direction
constexpr int GD = 32;         // h-dims per WG

// output layout (floats)
constexpr int EMB_OFF = 0;
constexpr int TOK_OFF = Bz * T1 * Dz;            // 4202496
constexpr int ALUT_OFF = TOK_OFF + Bz;           // 4202512
constexpr int USA_OFF = ALUT_OFF + Bz * T1;      // 4210720
constexpr int USP_OFF = USA_OFF + Bz * TU;       // 4235296

typedef short bf16x8 __attribute__((ext_vector_type(8)));
typedef float f32x4 __attribute__((ext_vector_type(4)));
typedef unsigned long long u64;

__device__ __forceinline__ float sigm(float x) { return 1.0f / (1.0f + expf(-x)); }
__device__ __forceinline__ float fsigm(float x) { return 1.0f / (1.0f + __expf(-x)); }
__device__ __forceinline__ float ftanh(float x) {
    float e = __expf(2.0f * x);
    return 1.0f - 2.0f / (e + 1.0f);
}
__device__ __forceinline__ unsigned short f2bf(float f) {
    unsigned u = __float_as_uint(f);
    return (unsigned short)((u + 0x7fffu + ((u >> 16) & 1u)) >> 16);
}

// ---------------- K0a: transpose conv_w -> wt[(i*3+k)*512 + d] ----------------
__global__ void k_transpose_convw(const float* __restrict__ cw, float* __restrict__ wt) {
    __shared__ float tile[64][65];
    int dt = blockIdx.x * 64, ct = blockIdx.y * 64;
    int tx = threadIdx.x & 63, ty = threadIdx.x >> 6;
    for (int r = ty; r < 64; r += 4)
        tile[r][tx] = cw[(dt + r) * 1536 + ct + tx];
    __syncthreads();
    for (int r = ty; r < 64; r += 4)
        wt[(ct + r) * 512 + dt + tx] = tile[tx][r];
}

// ---------------- K0b: transpose up_w -> upt[(k*512+o)*512 + i] ----------------
__global__ void k_transpose_upw(const float* __restrict__ uw, float* __restrict__ upt) {
    __shared__ float tile[64][65];
    int it = blockIdx.x * 64, ct = blockIdx.y * 64;
    int tx = threadIdx.x & 63, ty = threadIdx.x >> 6;
    for (int r = ty; r < 64; r += 4)
        tile[r][tx] = uw[(it + r) * 1536 + ct + tx];
    __syncthreads();
    for (int r = ty; r < 64; r += 4) {
        int c = ct + r;
        int k = c % 3, o = c / 3;
        upt[(k * 512 + o) * 512 + it + tx] = tile[tx][r];
    }
}

// ---------------- K0c: gconst[dir*2048+g] = b_ih+b_hh+sum_o up_b[o]*w_ih[g][o] ----------------
__global__ void k_gconst(const float* __restrict__ wih_f, const float* __restrict__ bih_f,
                         const float* __restrict__ bhh_f, const float* __restrict__ wih_b,
                         const float* __restrict__ bih_b, const float* __restrict__ bhh_b,
                         const float* __restrict__ upb, float* __restrict__ gconst) {
    int g = blockIdx.x * 256 + threadIdx.x;   // 0..4095
    int dir = g >> 11, gg = g & 2047;
    const float* wih = dir ? wih_b : wih_f;
    const float* bi = dir ? bih_b : bih_f;
    const float* bh = dir ? bhh_b : bhh_f;
    float s = bi[gg] + bh[gg];
    const float4* w4 = (const float4*)(wih + (size_t)gg * 512);
    const float4* u4 = (const float4*)upb;
    for (int o = 0; o < 128; ++o) {
        float4 w = w4[o], u = u4[o];
        s += w.x * u.x + w.y * u.y + w.z * u.z + w.w * u.w;
    }
    gconst[g] = s;
}

// ---------------- K1: M[(dir*3+k)*2048+g][i] = sum_o wih[g][o]*upt[k][o][i], bf16 ----------------
__global__ void k_M(const float* __restrict__ wih_f, const float* __restrict__ wih_b,
                    const float* __restrict__ upt, unsigned short* __restrict__ Mh) {
    __shared__ float As[32][68];
    __shared__ float Bs[32][68];
    int z = blockIdx.z;
    int dir = z / 3, k = z % 3;
    const float* A = dir ? wih_b : wih_f;
    const float* Bt = upt + (size_t)k * 262144;
    int g0 = blockIdx.y * 64, i0 = blockIdx.x * 64;
    int tid = threadIdx.x;
    int tx = tid & 15, ty = tid >> 4;
    float acc[4][4] = {};
    for (int k0 = 0; k0 < 512; k0 += 32) {
#pragma unroll
        for (int e = 0; e < 8; ++e) {
            int idx = e * 256 + tid;
            int ko = idx & 31, gl = idx >> 5;
            As[ko][gl] = A[(size_t)(g0 + gl) * 512 + k0 + ko];
        }
#pragma unroll
        for (int e = 0; e < 8; ++e) {
            int idx = e * 256 + tid;
            int il = idx & 63, ko = idx >> 6;
            Bs[ko][il] = Bt[(size_t)(k0 + ko) * 512 + i0 + il];
        }
        __syncthreads();
#pragma unroll
        for (int ko = 0; ko < 32; ++ko) {
            float4 a = *(const float4*)&As[ko][ty * 4];
            float4 b = *(const float4*)&Bs[ko][tx * 4];
            acc[0][0] += a.x * b.x; acc[0][1] += a.x * b.y; acc[0][2] += a.x * b.z; acc[0][3] += a.x * b.w;
            acc[1][0] += a.y * b.x; acc[1][1] += a.y * b.y; acc[1][2] += a.y * b.z; acc[1][3] += a.y * b.w;
            acc[2][0] += a.z * b.x; acc[2][1] += a.z * b.y; acc[2][2] += a.z * b.z; acc[2][3] += a.z * b.w;
            acc[3][0] += a.w * b.x; acc[3][1] += a.w * b.y; acc[3][2] += a.w * b.z; acc[3][3] += a.w * b.w;
        }
        __syncthreads();
    }
#pragma unroll
    for (int r = 0; r < 4; ++r) {
        ushort4 wh;
        wh.x = f2bf(acc[r][0]); wh.y = f2bf(acc[r][1]);
        wh.z = f2bf(acc[r][2]); wh.w = f2bf(acc[r][3]);
        *(ushort4*)&Mh[((size_t)(z * 2048 + g0 + ty * 4 + r)) * 512 + i0 + tx * 4] = wh;
    }
}

// ---------------- K1b: hidden -> bf16 ----------------
__global__ void k_Hbf(const float* __restrict__ hidden, unsigned short* __restrict__ Hs) {
    int i = blockIdx.x * 256 + threadIdx.x;   // handles 4 floats
    float4 v = *(const float4*)&hidden[(size_t)i * 4];
    ushort4 h4;
    h4.x = f2bf(v.x); h4.y = f2bf(v.y); h4.z = f2bf(v.z); h4.w = f2bf(v.w);
    *(ushort4*)&Hs[(size_t)i * 4] = h4;
}

// ---------------- K2: conv1d(pad1,k3)+relu then dot(out_w)+sigmoid -> alphas_s[b][s] ----------------
__global__ void k_conv_alpha(const float* __restrict__ hidden, const float* __restrict__ wt,
                             const float* __restrict__ cb, const float* __restrict__ ow,
                             const float* __restrict__ ob, const float* __restrict__ mask,
                             float* __restrict__ alph_s) {
    __shared__ float hs[18 * 512];
    __shared__ float red[16][257];
    int b = blockIdx.x, s0 = blockIdx.y * 16;
    int tid = threadIdx.x;
#pragma unroll
    for (int e = 0; e < 36; ++e) {
        int idx = e * 256 + tid;
        int r = idx >> 9, i = idx & 511;
        int s = s0 + r - 1;
        hs[idx] = (s >= 0 && s < Sz) ? hidden[((size_t)b * Sz + s) * Dz + i] : 0.f;
    }
    __syncthreads();
    float acc0[16] = {}, acc1[16] = {};
    int d0 = tid, d1 = tid + 256;
    for (int i = 0; i < 512; ++i) {
        float w00 = wt[(i * 3 + 0) * 512 + d0];
        float w01 = wt[(i * 3 + 1) * 512 + d0];
        float w02 = wt[(i * 3 + 2) * 512 + d0];
        float w10 = wt[(i * 3 + 0) * 512 + d1];
        float w11 = wt[(i * 3 + 1) * 512 + d1];
        float w12 = wt[(i * 3 + 2) * 512 + d1];
        float hv[18];
#pragma unroll
        for (int r = 0; r < 18; ++r) hv[r] = hs[r * 512 + i];
#pragma unroll
        for (int j = 0; j < 16; ++j) {
            acc0[j] += hv[j] * w00 + hv[j + 1] * w01 + hv[j + 2] * w02;
            acc1[j] += hv[j] * w10 + hv[j + 1] * w11 + hv[j + 2] * w12;
        }
    }
    float cb0 = cb[d0], cb1 = cb[d1], ow0 = ow[d0], ow1 = ow[d1];
#pragma unroll
    for (int j = 0; j < 16; ++j)
        red[j][tid] = fmaxf(acc0[j] + cb0, 0.f) * ow0 + fmaxf(acc1[j] + cb1, 0.f) * ow1;
    __syncthreads();
    for (int off = 128; off >= 1; off >>= 1) {
        if (tid < off) {
#pragma unroll
            for (int j = 0; j < 16; ++j) red[j][tid] += red[j][tid + off];
        }
        __syncthreads();
    }
    if (tid < 16) {
        float v = red[tid][0] + ob[0];
        float a = sigm(v);
        a = fmaxf(a * SM1c - NT1c, 0.f);
        a *= mask[b * Sz + s0 + tid];
        alph_s[b * Sz + s0 + tid] = a;
    }
}

// ---------------- K3: CIF scalar scan (serial per batch) ----------------
__global__ void k_cif_scan(const float* __restrict__ alph_s, const float* __restrict__ mask,
                           float* __restrict__ out, float* __restrict__ sc_cur,
                           float* __restrict__ sc_res, int* __restrict__ sc_dst) {
    __shared__ float sa[16][T1];
    int tid = threadIdx.x;
    for (int idx = tid; idx < 16 * T1; idx += 256) {
        int b = idx / T1, t = idx % T1;
        float a = (t < Sz) ? alph_s[b * Sz + t] : 0.f;
        float mp = (t == 0) ? 1.f : mask[b * Sz + t - 1];
        float mc = (t < Sz) ? mask[b * Sz + t] : 0.f;
        sa[b][t] = a + (mp - mc) * TAILc;
    }
    __syncthreads();
    if (tid < 16) {
        int b = tid;
        float integ = 0.f, sum = 0.f;
        int nf = 0;
        for (int t = 0; t < T1; ++t) {
            float a = sa[b][t];
            out[ALUT_OFF + b * T1 + t] = a;
            sum += a;
            float dist = 1.f - integ;
            integ += a;
            bool fire = (integ >= THRESHc);
            float cur = fire ? dist : a;
            sc_cur[b * T1 + t] = cur;
            sc_res[b * T1 + t] = fire ? (a - cur) : 0.f;
            sc_dst[b * T1 + t] = fire ? (nf++) : -1;
            if (fire) integ -= 1.f;
        }
        out[TOK_OFF + b] = floorf(sum);
    }
}

// ---------------- K4: CIF frame accumulation / scatter ----------------
__global__ void k_cif_frames(const float* __restrict__ hidden, const float* __restrict__ sc_cur,
                             const float* __restrict__ sc_res, const int* __restrict__ sc_dst,
                             float* __restrict__ out) {
    __shared__ float cu[T1], re[T1];
    __shared__ int dsx[T1];
    int b = blockIdx.x, d = blockIdx.y * 256 + threadIdx.x;
    for (int t = threadIdx.x; t < T1; t += 256) {
        cu[t] = sc_cur[b * T1 + t];
        re[t] = sc_res[b * T1 + t];
        dsx[t] = sc_dst[b * T1 + t];
    }
    __syncthreads();
    float frame = 0.f;
    for (int t = 0; t < T1; ++t) {
        float ht = (t < Sz) ? hidden[((size_t)b * Sz + t) * Dz + d] : 0.f;
        float f = frame + cu[t] * ht;
        int dst = dsx[t];
        if (dst >= 0) {
            out[EMB_OFF + ((size_t)b * T1 + dst) * Dz + d] = f;
            frame = re[t] * ht;
        } else {
            frame = f;
        }
    }
}

// ---------------- K5: persistent cooperative BiLSTM v9 ----------------
// r5 protocol (store h -> wave-local vmcnt drain -> prog store -> poll -> single
// gather) with HALF the sync group (16 WGs/direction, 32 dims each, 2 MFMA
// row-tiles, whA in 128 VGPRs), fully parallel cell (2 cells/thread), and the
// us-partial on wave1 (off wave0's drain->prog critical path).
__global__ void __launch_bounds__(256, 1)
k_lstm(const unsigned short* __restrict__ Mh, const unsigned short* __restrict__ Hs,
       const float* __restrict__ whh_f, const float* __restrict__ whh_b,
       const float* __restrict__ gconst, const float* __restrict__ w2,
       unsigned short* hX, float* part, int* prog) {
    __shared__ unsigned short hbuf[16 * 512];   // gathered h (swizzled, batch rows)
    __shared__ float xch[4 * 32 * 17];          // [gate][dim][batch] padded
    __shared__ float pbuf[32 * 17];             // us partials [dim][batch]
    __shared__ unsigned short hout[16 * 32];    // new h [batch][dim]

    const int wg = blockIdx.x;                  // 0..31
    const int dir = wg >> 4, slice = wg & 15;
    const int d0 = slice * GD;
    const int tid = threadIdx.x;
    const int wv = tid >> 6;                    // wave = gate (0:i 1:f 2:g 3:o)
    const int l = tid & 63;
    const int colb = l & 15;                    // batch col (A row / B col)
    const int khi = l >> 4;
    const float* whh = dir ? whh_b : whh_f;

    // one-time: W_hh bf16 fragments (2 row tiles x 16 k-chunks) in registers
    bf16x8 whA0[16], whA1[16];
#pragma unroll
    for (int rt = 0; rt < 2; ++rt) {
        const float* wr = whh + (size_t)(wv * 512 + d0 + rt * 16 + colb) * 512 + khi * 8;
#pragma unroll
        for (int m = 0; m < 16; ++m) {
            float4 a = *(const float4*)(wr + m * 32);
            float4 b = *(const float4*)(wr + m * 32 + 4);
            union { unsigned short u[8]; bf16x8 v; } hh;
            hh.u[0] = f2bf(a.x); hh.u[1] = f2bf(a.y); hh.u[2] = f2bf(a.z); hh.u[3] = f2bf(a.w);
            hh.u[4] = f2bf(b.x); hh.u[5] = f2bf(b.y); hh.u[6] = f2bf(b.z); hh.u[7] = f2bf(b.w);
            if (rt == 0) whA0[m] = hh.v; else whA1[m] = hh.v;
        }
    }

    f32x4 bias0, bias1;
#pragma unroll
    for (int j = 0; j < 4; ++j) {
        bias0[j] = gconst[dir * 2048 + wv * 512 + d0 + khi * 4 + j];
        bias1[j] = gconst[dir * 2048 + wv * 512 + d0 + 16 + khi * 4 + j];
    }
    // cell ownership: batch cb = tid>>4, dims cd0, cd0+1
    const int cb = tid >> 4;
    const int cd0 = (tid & 15) * 2;
    const float w20 = w2[dir * 512 + d0 + cd0];
    const float w21 = w2[dir * 512 + d0 + cd0 + 1];
    float cs0 = 0.f, cs1 = 0.f;

    int* myprog = prog + (dir * SLD + slice) * 16;
    const int* pollp = prog + (dir * SLD + (l & 15)) * 16;

    auto idot = [&](int n, f32x4& a0, f32x4& a1) {
        int t = dir ? (TU - 1 - n) : n;
        int s = t / 3, k = t - 3 * s;
        const unsigned short* ma0 = Mh + ((size_t)((dir * 3 + k) * 2048 + wv * 512 + d0 + colb)) * 512 + khi * 8;
        const unsigned short* ma1 = ma0 + (size_t)16 * 512;
        const unsigned short* xa = Hs + ((size_t)(colb * 512 + s)) * 512 + khi * 8;
        a0 = bias0; a1 = bias1;
#pragma unroll
        for (int m = 0; m < 16; ++m) {
            bf16x8 B = *(const bf16x8*)(xa + m * 32);
            bf16x8 A0 = *(const bf16x8*)(ma0 + m * 32);
            bf16x8 A1 = *(const bf16x8*)(ma1 + m * 32);
            a0 = __builtin_amdgcn_mfma_f32_16x16x32_bf16(A0, B, a0, 0, 0, 0);
            a1 = __builtin_amdgcn_mfma_f32_16x16x32_bf16(A1, B, a1, 0, 0, 0);
        }
    };

    f32x4 acc0, acc1;
    idot(0, acc0, acc1);

    for (int n = 0; n < TU; ++n) {
        int t = dir ? (TU - 1 - n) : n;
        if (n > 0) {
            // ---- 1. poll 16 prog counters (lanes spread across them) ----
            {
                int it = 0;
                while (true) {
                    int v;
                    asm volatile("global_load_dword %0, %1, off sc0 sc1\n\ts_waitcnt vmcnt(0)"
                                 : "=v"(v) : "v"(pollp));
                    if (__ballot(v >= n) == ~0ull) break;
                    if (++it > (1 << 15)) break;
                }
            }
            // ---- 2. single 16KB coherent gather of h[n-1] ----
            const unsigned short* hb = hX + (size_t)((dir * 2 + ((n - 1) & 1)) * 16 + (tid >> 4)) * 512 + (tid & 15) * 32;
            bf16x8 g0, g1, g2, g3;
            asm volatile("global_load_dwordx4 %0, %1, off sc0 sc1" : "=v"(g0) : "v"(hb));
            asm volatile("global_load_dwordx4 %0, %1, off sc0 sc1" : "=v"(g1) : "v"(hb + 8));
            asm volatile("global_load_dwordx4 %0, %1, off sc0 sc1" : "=v"(g2) : "v"(hb + 16));
            asm volatile("global_load_dwordx4 %0, %1, off sc0 sc1" : "=v"(g3) : "v"(hb + 24));
            asm volatile("s_waitcnt vmcnt(0)" ::: "memory");
            __builtin_amdgcn_sched_barrier(0);
            // ---- 3. unpack to swizzled LDS ----
            {
                int batch = tid >> 4, ch = tid & 15;
                int gq = ch * 4;
                *(bf16x8*)&hbuf[batch * 512 + (((gq + 0) ^ (batch & 7)) << 3)] = g0;
                *(bf16x8*)&hbuf[batch * 512 + (((gq + 1) ^ (batch & 7)) << 3)] = g1;
                *(bf16x8*)&hbuf[batch * 512 + (((gq + 2) ^ (batch & 7)) << 3)] = g2;
                *(bf16x8*)&hbuf[batch * 512 + (((gq + 3) ^ (batch & 7)) << 3)] = g3;
            }
            __syncthreads();
            // ---- 4. hhdot: 2 row tiles, resident weights ----
#pragma unroll
            for (int m = 0; m < 16; ++m) {
                bf16x8 B = *(const bf16x8*)&hbuf[colb * 512 + (((m * 4 + khi) ^ (colb & 7)) << 3)];
                acc0 = __builtin_amdgcn_mfma_f32_16x16x32_bf16(whA0[m], B, acc0, 0, 0, 0);
                acc1 = __builtin_amdgcn_mfma_f32_16x16x32_bf16(whA1[m], B, acc1, 0, 0, 0);
            }
        }
        // ---- 5. gates -> padded LDS ----
#pragma unroll
        for (int j = 0; j < 4; ++j) {
            xch[wv * 544 + (khi * 4 + j) * 17 + colb] = acc0[j];
            xch[wv * 544 + (16 + khi * 4 + j) * 17 + colb] = acc1[j];
        }
        __syncthreads();
        // ---- 6. cell: 2 (dim,batch) cells per thread ----
        {
            float gi0 = xch[0 * 544 + cd0 * 17 + cb];
            float gf0 = xch[1 * 544 + cd0 * 17 + cb];
            float gg0 = xch[2 * 544 + cd0 * 17 + cb];
            float go0 = xch[3 * 544 + cd0 * 17 + cb];
            float gi1 = xch[0 * 544 + (cd0 + 1) * 17 + cb];
            float gf1 = xch[1 * 544 + (cd0 + 1) * 17 + cb];
            float gg1 = xch[2 * 544 + (cd0 + 1) * 17 + cb];
            float go1 = xch[3 * 544 + (cd0 + 1) * 17 + cb];
            float c0 = fsigm(gf0) * cs0 + fsigm(gi0) * ftanh(gg0);
            float c1 = fsigm(gf1) * cs1 + fsigm(gi1) * ftanh(gg1);
            cs0 = c0; cs1 = c1;
            float h0 = fsigm(go0) * ftanh(c0);
            float h1 = fsigm(go1) * ftanh(c1);
            unsigned hw = (unsigned)f2bf(h0) | ((unsigned)f2bf(h1) << 16);
            *(unsigned*)&hout[cb * 32 + cd0] = hw;
            pbuf[cd0 * 17 + cb] = h0 * w20;
            pbuf[(cd0 + 1) * 17 + cb] = h1 * w21;
        }
        __syncthreads();
        // ---- 7. wave0: pack h stripe, coherent store, drain, prog ----
        if (wv == 0) {
            int b = l >> 2, g4 = l & 3;
            bf16x8 hv = *(const bf16x8*)&hout[b * 32 + g4 * 8];
            unsigned short* dst = hX + (size_t)((dir * 2 + (n & 1)) * 16 + b) * 512 + d0 + g4 * 8;
            asm volatile("global_store_dwordx4 %0, %1, off sc0 sc1"
                         :: "v"(dst), "v"(hv) : "memory");
            asm volatile("s_waitcnt vmcnt(0)" ::: "memory");   // h visible before prog
            if (l == 0) {
                int nv = n + 1;
                asm volatile("global_store_dword %0, %1, off sc0 sc1"
                             :: "v"(myprog), "v"(nv) : "memory");
            }
        }
        // ---- 8. wave1: us-partial reduce + store (off critical path) ----
        if (wv == 1 && l < 16) {
            float s = 0.f;
#pragma unroll
            for (int d = 0; d < 32; ++d) s += pbuf[d * 17 + l];
            part[((size_t)((dir * SLD + slice) * 16) + l) * TU + t] = s;
        }
        // ---- 9. next-step input dot (overlaps others' poll window) ----
        if (n + 1 < TU) idot(n + 1, acc0, acc1);
    }
}

// ---------------- K6: reduce us partials, activation, pre-norm ----------------
__global__ void k_us_reduce(const float* __restrict__ part, const float* __restrict__ ob2,
                            const float* __restrict__ mask, float* __restrict__ usA,
                            float* __restrict__ csum) {
    int b = blockIdx.x, ch = blockIdx.y;
    int t = ch * 256 + threadIdx.x;
    float s = 0.f;
#pragma unroll 8
    for (int p = 0; p < 32; ++p) s += part[((size_t)p * Bz + b) * TU + t];
    float u = sigm(s + ob2[0]);
    float ua = fmaxf(u * SM2c - NT2c, 0.f) * mask[b * Sz + t / 3];
    usA[b * TU + t] = ua;
    __shared__ float red[256];
    red[threadIdx.x] = ua;
    __syncthreads();
    for (int off = 128; off >= 1; off >>= 1) {
        if (threadIdx.x < off) red[threadIdx.x] += red[threadIdx.x + off];
        __syncthreads();
    }
    if (threadIdx.x == 0) csum[b * 6 + ch] = red[0];
}

// ---------------- K7: normalize + peak scan (serial per batch) ----------------
__global__ void k_us_scan(const float* __restrict__ usA, const float* __restrict__ csum,
                          float* __restrict__ out) {
    __shared__ float ubuf[TU];
    int b = blockIdx.x;
    for (int t = threadIdx.x; t < TU; t += 64) ubuf[t] = usA[b * TU + t];
    __syncthreads();
    if (threadIdx.x == 0) {
        float tot = 0.f;
        for (int c = 0; c < 6; ++c) tot += csum[b * 6 + c];
        float scale = out[TOK_OFF + b] / tot;
        float integ = 0.f;
        const float th = THRESHc - 0.0001f;
        for (int t = 0; t < TU; ++t) {
            float ua = ubuf[t] * scale;
            out[USA_OFF + b * TU + t] = ua;
            integ += ua;
            out[USP_OFF + b * TU + t] = integ;
            if (integ >= th) integ -= th;
        }
    }
}

// ---------------- host ----------------
extern "C" void kernel_launch(void* const* d_in, const int* in_sizes, int n_in,
                              void* d_out, int out_size, void* d_ws, size_t ws_size,
                              hipStream_t stream) {
    const float* hidden = (const float*)d_in[0];
    const float* mask   = (const float*)d_in[1];
    const float* conv_w = (const float*)d_in[2];
    const float* conv_b = (const float*)d_in[3];
    const float* out_w  = (const float*)d_in[4];
    const float* out_b  = (const float*)d_in[5];
    const float* up_w   = (const float*)d_in[6];
    const float* up_b   = (const float*)d_in[7];
    const float* w_ih_f = (const float*)d_in[8];
    const float* w_hh_f = (const float*)d_in[9];
    const float* b_ih_f = (const float*)d_in[10];
    const float* b_hh_f = (const float*)d_in[11];
    const float* w_ih_b = (const float*)d_in[12];
    const float* w_hh_b = (const float*)d_in[13];
    const float* b_ih_b = (const float*)d_in[14];
    const float* b_hh_b = (const float*)d_in[15];
    const float* out2_w = (const float*)d_in[16];
    const float* out2_b = (const float*)d_in[17];
    float* out = (float*)d_out;
    float* ws = (float*)d_ws;

    // workspace layout (float slots), ~8.49M floats = 34.0 MB
    float* wt     = ws + 0;              // 786,432
    float* upt    = ws + 786432;         // 786,432
    float* part   = ws + 1572864;        // 786,432 used (32*16*TU)
    float* gconst = ws + 3145728;        // 4096
    float* alph_s = ws + 3149824;        // 8192
    float* sc_cur = ws + 3158016;        // 8208
    float* sc_res = ws + 3166224;        // 8208
    int*   sc_dst = (int*)(ws + 3174432);            // 8208
    float* usA    = ws + 3182640;        // 24576
    float* csum   = ws + 3207216;        // 96
    unsigned short* Mh = (unsigned short*)(ws + 3207312);   // 6,291,456 shorts
    unsigned short* Hs = (unsigned short*)(ws + 6353040);   // 4,194,304 shorts
    unsigned short* hX = (unsigned short*)(ws + 8450192);   // 32768 shorts (64 KB)
    int*   prog   = (int*)(ws + 8482960);            // 1024 ints (32 counters, 64B stride)

    hipMemsetAsync(out, 0, (size_t)Bz * T1 * Dz * sizeof(float), stream);   // embeds region
    hipMemsetAsync(prog, 0, 1024 * sizeof(int), stream);

    k_transpose_convw<<<dim3(8, 24), 256, 0, stream>>>(conv_w, wt);
    k_transpose_upw<<<dim3(8, 24), 256, 0, stream>>>(up_w, upt);
    k_gconst<<<16, 256, 0, stream>>>(w_ih_f, b_ih_f, b_hh_f, w_ih_b, b_ih_b, b_hh_b, up_b, gconst);
    k_M<<<dim3(8, 32, 6), 256, 0, stream>>>(w_ih_f, w_ih_b, upt, Mh);
    k_Hbf<<<4096, 256, 0, stream>>>(hidden, Hs);
    k_conv_alpha<<<dim3(16, 32), 256, 0, stream>>>(hidden, wt, conv_b, out_w, out_b, mask, alph_s);
    k_cif_scan<<<1, 256, 0, stream>>>(alph_s, mask, out, sc_cur, sc_res, sc_dst);
    k_cif_frames<<<dim3(16, 2), 256, 0, stream>>>(hidden, sc_cur, sc_res, sc_dst, out);

    {
        void* args[] = { (void*)&Mh, (void*)&Hs, (void*)&w_hh_f, (void*)&w_hh_b,
                         (void*)&gconst, (void*)&out2_w, (void*)&hX, (void*)&part,
                         (void*)&prog };
        hipLaunchCooperativeKernel(reinterpret_cast<void*>(&k_lstm), dim3(32), dim3(256),
                                   args, 0, stream);
    }

    k_us_reduce<<<dim3(16, 6), 256, 0, stream>>>(part, out2_b, mask, usA, csum);
    k_us_scan<<<16, 64, 0, stream>>>(usA, csum, out);
}

// Round 12
// 10121.517 us; speedup vs baseline: 1.8288x; 1.2518x over previous
//
#include <hip/hip_runtime.h>
#include <math.h>

// ---------------- problem constants ----------------
constexpr int Bz = 16;
constexpr int Sz = 512;
constexpr int Dz = 512;
constexpr int T1 = Sz + 1;     // 513
constexpr int TU = Sz * 3;     // 1536
constexpr float THRESHc = 1.0f;
constexpr float SM1c = 1.0f, NT1c = 0.0f;
constexpr float TAILc = 0.45f;
constexpr float SM2c = 0.25f, NT2c = 0.01f;

// LSTM persistent-kernel geometry
constexpr int GD = 16;         // h-dims per WG (32 WGs per direction, grid 64)

// output layout (floats)
constexpr int EMB_OFF = 0;
constexpr int TOK_OFF = Bz * T1 * Dz;            // 4202496
constexpr int ALUT_OFF = TOK_OFF + Bz;           // 4202512
constexpr int USA_OFF = ALUT_OFF + Bz * T1;      // 4210720
constexpr int USP_OFF = USA_OFF + Bz * TU;       // 4235296

typedef short bf16x8 __attribute__((ext_vector_type(8)));
typedef float f32x4 __attribute__((ext_vector_type(4)));
typedef unsigned long long u64;

__device__ __forceinline__ float sigm(float x) { return 1.0f / (1.0f + expf(-x)); }
__device__ __forceinline__ float fsigm(float x) { return 1.0f / (1.0f + __expf(-x)); }
__device__ __forceinline__ float ftanh(float x) {
    float e = __expf(2.0f * x);
    return 1.0f - 2.0f / (e + 1.0f);
}
__device__ __forceinline__ unsigned short f2bf(float f) {
    unsigned u = __float_as_uint(f);
    return (unsigned short)((u + 0x7fffu + ((u >> 16) & 1u)) >> 16);
}

// ---------------- K0a: transpose conv_w -> wt[(i*3+k)*512 + d] ----------------
__global__ void k_transpose_convw(const float* __restrict__ cw, float* __restrict__ wt) {
    __shared__ float tile[64][65];
    int dt = blockIdx.x * 64, ct = blockIdx.y * 64;
    int tx = threadIdx.x & 63, ty = threadIdx.x >> 6;
    for (int r = ty; r < 64; r += 4)
        tile[r][tx] = cw[(dt + r) * 1536 + ct + tx];
    __syncthreads();
    for (int r = ty; r < 64; r += 4)
        wt[(ct + r) * 512 + dt + tx] = tile[tx][r];
}

// ---------------- K0b: transpose up_w -> upt[(k*512+o)*512 + i] ----------------
__global__ void k_transpose_upw(const float* __restrict__ uw, float* __restrict__ upt) {
    __shared__ float tile[64][65];
    int it = blockIdx.x * 64, ct = blockIdx.y * 64;
    int tx = threadIdx.x & 63, ty = threadIdx.x >> 6;
    for (int r = ty; r < 64; r += 4)
        tile[r][tx] = uw[(it + r) * 1536 + ct + tx];
    __syncthreads();
    for (int r = ty; r < 64; r += 4) {
        int c = ct + r;
        int k = c % 3, o = c / 3;
        upt[(k * 512 + o) * 512 + it + tx] = tile[tx][r];
    }
}

// ---------------- K0c: gconst[dir*2048+g] = b_ih+b_hh+sum_o up_b[o]*w_ih[g][o] ----------------
__global__ void k_gconst(const float* __restrict__ wih_f, const float* __restrict__ bih_f,
                         const float* __restrict__ bhh_f, const float* __restrict__ wih_b,
                         const float* __restrict__ bih_b, const float* __restrict__ bhh_b,
                         const float* __restrict__ upb, float* __restrict__ gconst) {
    int g = blockIdx.x * 256 + threadIdx.x;   // 0..4095
    int dir = g >> 11, gg = g & 2047;
    const float* wih = dir ? wih_b : wih_f;
    const float* bi = dir ? bih_b : bih_f;
    const float* bh = dir ? bhh_b : bhh_f;
    float s = bi[gg] + bh[gg];
    const float4* w4 = (const float4*)(wih + (size_t)gg * 512);
    const float4* u4 = (const float4*)upb;
    for (int o = 0; o < 128; ++o) {
        float4 w = w4[o], u = u4[o];
        s += w.x * u.x + w.y * u.y + w.z * u.z + w.w * u.w;
    }
    gconst[g] = s;
}

// ---------------- K1: M[(dir*3+k)*2048+g][i] = sum_o wih[g][o]*upt[k][o][i], bf16 ----------------
__global__ void k_M(const float* __restrict__ wih_f, const float* __restrict__ wih_b,
                    const float* __restrict__ upt, unsigned short* __restrict__ Mh) {
    __shared__ float As[32][68];
    __shared__ float Bs[32][68];
    int z = blockIdx.z;
    int dir = z / 3, k = z % 3;
    const float* A = dir ? wih_b : wih_f;
    const float* Bt = upt + (size_t)k * 262144;
    int g0 = blockIdx.y * 64, i0 = blockIdx.x * 64;
    int tid = threadIdx.x;
    int tx = tid & 15, ty = tid >> 4;
    float acc[4][4] = {};
    for (int k0 = 0; k0 < 512; k0 += 32) {
#pragma unroll
        for (int e = 0; e < 8; ++e) {
            int idx = e * 256 + tid;
            int ko = idx & 31, gl = idx >> 5;
            As[ko][gl] = A[(size_t)(g0 + gl) * 512 + k0 + ko];
        }
#pragma unroll
        for (int e = 0; e < 8; ++e) {
            int idx = e * 256 + tid;
            int il = idx & 63, ko = idx >> 6;
            Bs[ko][il] = Bt[(size_t)(k0 + ko) * 512 + i0 + il];
        }
        __syncthreads();
#pragma unroll
        for (int ko = 0; ko < 32; ++ko) {
            float4 a = *(const float4*)&As[ko][ty * 4];
            float4 b = *(const float4*)&Bs[ko][tx * 4];
            acc[0][0] += a.x * b.x; acc[0][1] += a.x * b.y; acc[0][2] += a.x * b.z; acc[0][3] += a.x * b.w;
            acc[1][0] += a.y * b.x; acc[1][1] += a.y * b.y; acc[1][2] += a.y * b.z; acc[1][3] += a.y * b.w;
            acc[2][0] += a.z * b.x; acc[2][1] += a.z * b.y; acc[2][2] += a.z * b.z; acc[2][3] += a.z * b.w;
            acc[3][0] += a.w * b.x; acc[3][1] += a.w * b.y; acc[3][2] += a.w * b.z; acc[3][3] += a.w * b.w;
        }
        __syncthreads();
    }
#pragma unroll
    for (int r = 0; r < 4; ++r) {
        ushort4 wh;
        wh.x = f2bf(acc[r][0]); wh.y = f2bf(acc[r][1]);
        wh.z = f2bf(acc[r][2]); wh.w = f2bf(acc[r][3]);
        *(ushort4*)&Mh[((size_t)(z * 2048 + g0 + ty * 4 + r)) * 512 + i0 + tx * 4] = wh;
    }
}

// ---------------- K1b: hidden -> bf16 ----------------
__global__ void k_Hbf(const float* __restrict__ hidden, unsigned short* __restrict__ Hs) {
    int i = blockIdx.x * 256 + threadIdx.x;   // handles 4 floats
    float4 v = *(const float4*)&hidden[(size_t)i * 4];
    ushort4 h4;
    h4.x = f2bf(v.x); h4.y = f2bf(v.y); h4.z = f2bf(v.z); h4.w = f2bf(v.w);
    *(ushort4*)&Hs[(size_t)i * 4] = h4;
}

// ---------------- K2: conv1d(pad1,k3)+relu then dot(out_w)+sigmoid -> alphas_s[b][s] ----------------
__global__ void k_conv_alpha(const float* __restrict__ hidden, const float* __restrict__ wt,
                             const float* __restrict__ cb, const float* __restrict__ ow,
                             const float* __restrict__ ob, const float* __restrict__ mask,
                             float* __restrict__ alph_s) {
    __shared__ float hs[18 * 512];
    __shared__ float red[16][257];
    int b = blockIdx.x, s0 = blockIdx.y * 16;
    int tid = threadIdx.x;
#pragma unroll
    for (int e = 0; e < 36; ++e) {
        int idx = e * 256 + tid;
        int r = idx >> 9, i = idx & 511;
        int s = s0 + r - 1;
        hs[idx] = (s >= 0 && s < Sz) ? hidden[((size_t)b * Sz + s) * Dz + i] : 0.f;
    }
    __syncthreads();
    float acc0[16] = {}, acc1[16] = {};
    int d0 = tid, d1 = tid + 256;
    for (int i = 0; i < 512; ++i) {
        float w00 = wt[(i * 3 + 0) * 512 + d0];
        float w01 = wt[(i * 3 + 1) * 512 + d0];
        float w02 = wt[(i * 3 + 2) * 512 + d0];
        float w10 = wt[(i * 3 + 0) * 512 + d1];
        float w11 = wt[(i * 3 + 1) * 512 + d1];
        float w12 = wt[(i * 3 + 2) * 512 + d1];
        float hv[18];
#pragma unroll
        for (int r = 0; r < 18; ++r) hv[r] = hs[r * 512 + i];
#pragma unroll
        for (int j = 0; j < 16; ++j) {
            acc0[j] += hv[j] * w00 + hv[j + 1] * w01 + hv[j + 2] * w02;
            acc1[j] += hv[j] * w10 + hv[j + 1] * w11 + hv[j + 2] * w12;
        }
    }
    float cb0 = cb[d0], cb1 = cb[d1], ow0 = ow[d0], ow1 = ow[d1];
#pragma unroll
    for (int j = 0; j < 16; ++j)
        red[j][tid] = fmaxf(acc0[j] + cb0, 0.f) * ow0 + fmaxf(acc1[j] + cb1, 0.f) * ow1;
    __syncthreads();
    for (int off = 128; off >= 1; off >>= 1) {
        if (tid < off) {
#pragma unroll
            for (int j = 0; j < 16; ++j) red[j][tid] += red[j][tid + off];
        }
        __syncthreads();
    }
    if (tid < 16) {
        float v = red[tid][0] + ob[0];
        float a = sigm(v);
        a = fmaxf(a * SM1c - NT1c, 0.f);
        a *= mask[b * Sz + s0 + tid];
        alph_s[b * Sz + s0 + tid] = a;
    }
}

// ---------------- K3: CIF scalar scan (serial per batch) ----------------
__global__ void k_cif_scan(const float* __restrict__ alph_s, const float* __restrict__ mask,
                           float* __restrict__ out, float* __restrict__ sc_cur,
                           float* __restrict__ sc_res, int* __restrict__ sc_dst) {
    __shared__ float sa[16][T1];
    int tid = threadIdx.x;
    for (int idx = tid; idx < 16 * T1; idx += 256) {
        int b = idx / T1, t = idx % T1;
        float a = (t < Sz) ? alph_s[b * Sz + t] : 0.f;
        float mp = (t == 0) ? 1.f : mask[b * Sz + t - 1];
        float mc = (t < Sz) ? mask[b * Sz + t] : 0.f;
        sa[b][t] = a + (mp - mc) * TAILc;
    }
    __syncthreads();
    if (tid < 16) {
        int b = tid;
        float integ = 0.f, sum = 0.f;
        int nf = 0;
        for (int t = 0; t < T1; ++t) {
            float a = sa[b][t];
            out[ALUT_OFF + b * T1 + t] = a;
            sum += a;
            float dist = 1.f - integ;
            integ += a;
            bool fire = (integ >= THRESHc);
            float cur = fire ? dist : a;
            sc_cur[b * T1 + t] = cur;
            sc_res[b * T1 + t] = fire ? (a - cur) : 0.f;
            sc_dst[b * T1 + t] = fire ? (nf++) : -1;
            if (fire) integ -= 1.f;
        }
        out[TOK_OFF + b] = floorf(sum);
    }
}

// ---------------- K4: CIF frame accumulation / scatter ----------------
__global__ void k_cif_frames(const float* __restrict__ hidden, const float* __restrict__ sc_cur,
                             const float* __restrict__ sc_res, const int* __restrict__ sc_dst,
                             float* __restrict__ out) {
    __shared__ float cu[T1], re[T1];
    __shared__ int dsx[T1];
    int b = blockIdx.x, d = blockIdx.y * 256 + threadIdx.x;
    for (int t = threadIdx.x; t < T1; t += 256) {
        cu[t] = sc_cur[b * T1 + t];
        re[t] = sc_res[b * T1 + t];
        dsx[t] = sc_dst[b * T1 + t];
    }
    __syncthreads();
    float frame = 0.f;
    for (int t = 0; t < T1; ++t) {
        float ht = (t < Sz) ? hidden[((size_t)b * Sz + t) * Dz + d] : 0.f;
        float f = frame + cu[t] * ht;
        int dst = dsx[t];
        if (dst >= 0) {
            out[EMB_OFF + ((size_t)b * T1 + dst) * Dz + d] = f;
            frame = re[t] * ht;
        } else {
            frame = f;
        }
    }
}

// ---------------- K5: persistent cooperative BiLSTM v5 ----------------
// bf16-only; W_hh in regs; per-WG progress counters (no atomics); swizzled LDS h-buffer;
// idot(n+1) after cell phase; vmcnt(0) covers only the 4-coherent-load gather.
__global__ void __launch_bounds__(256, 1)
k_lstm(const unsigned short* __restrict__ Mh, const unsigned short* __restrict__ Hs,
       const float* __restrict__ whh_f, const float* __restrict__ whh_b,
       const float* __restrict__ gconst, const float* __restrict__ w2,
       unsigned short* hX, float* part, int* prog) {
    __shared__ unsigned short hbh[16 * 512];   // swizzled: row*512 + (G ^ (row&7))*8
    __shared__ float xch[3 * 256];

    const int wg = blockIdx.x;                 // 0..63
    const int dir = wg >> 5;
    const int slice = wg & 31;
    const int d0 = slice * GD;
    const int tid = threadIdx.x;
    const int wv = tid >> 6;                   // wave = gate (0:i 1:f 2:g 3:o)
    const int l = tid & 63;
    const int colb = l & 15;                   // batch
    const int khi = l >> 4;
    const float* whh = dir ? whh_b : whh_f;

    // one-time: W_hh bf16 fragments in registers
    bf16x8 whA[16];
    {
        const float* wr = whh + (size_t)(wv * 512 + d0 + colb) * 512 + khi * 8;
#pragma unroll
        for (int m = 0; m < 16; ++m) {
            float4 a = *(const float4*)(wr + m * 32);
            float4 b = *(const float4*)(wr + m * 32 + 4);
            union { unsigned short u[8]; bf16x8 v; } hh;
            hh.u[0] = f2bf(a.x); hh.u[1] = f2bf(a.y); hh.u[2] = f2bf(a.z); hh.u[3] = f2bf(a.w);
            hh.u[4] = f2bf(b.x); hh.u[5] = f2bf(b.y); hh.u[6] = f2bf(b.z); hh.u[7] = f2bf(b.w);
            whA[m] = hh.v;
        }
    }

    f32x4 bias;
    float w2v[4], cst[4] = {0.f, 0.f, 0.f, 0.f};
#pragma unroll
    for (int j = 0; j < 4; ++j) {
        bias[j] = gconst[dir * 2048 + wv * 512 + d0 + khi * 4 + j];
        w2v[j] = w2[dir * 512 + d0 + khi * 4 + j];
    }
    int* myprog = prog + (dir * 32 + slice) * 16;
    const int* pollp = prog + (dir * 32 + (l & 31)) * 16;

    auto idot = [&](int n) -> f32x4 {
        int t = dir ? (TU - 1 - n) : n;
        int s = t / 3, k = t - 3 * s;
        const unsigned short* ma = Mh + ((size_t)((dir * 3 + k) * 2048 + wv * 512 + d0 + colb)) * 512 + khi * 8;
        const unsigned short* xa = Hs + ((size_t)(colb * 512 + s)) * 512 + khi * 8;
        f32x4 a = bias;
#pragma unroll
        for (int m = 0; m < 16; ++m) {
            bf16x8 A = *(const bf16x8*)(ma + m * 32);
            bf16x8 B = *(const bf16x8*)(xa + m * 32);
            a = __builtin_amdgcn_mfma_f32_16x16x32_bf16(A, B, a, 0, 0, 0);
        }
        return a;
    };

    f32x4 accA = idot(0);

    for (int n = 0; n < TU; ++n) {
        int t = dir ? (TU - 1 - n) : n;
        if (n > 0) {
            // wave-parallel poll: all 32 WGs of this direction must have completed step n-1
            {
                int it = 0;
                while (true) {
                    int v;
                    asm volatile("global_load_dword %0, %1, off sc0 sc1\n\ts_waitcnt vmcnt(0)"
                                 : "=v"(v) : "v"(pollp));
                    if (__ballot(v >= n) == ~0ull) break;
                    if (++it > (1 << 15)) break;
                    __builtin_amdgcn_s_sleep(1);
                }
            }
            // coherent gather of h[n-1] (16 KB, coalesced) + swizzled LDS store
            int slot = (n - 1) & 1;
            const unsigned short* hb = hX + (size_t)((dir * 2 + slot) * 16) * 512;
            bf16x8 hg[4];
#pragma unroll
            for (int j = 0; j < 4; ++j)
                asm volatile("global_load_dwordx4 %0, %1, off sc0 sc1"
                             : "=v"(hg[j]) : "v"(hb + j * 2048 + tid * 8));
            asm volatile("s_waitcnt vmcnt(0)" ::: "memory");
            __builtin_amdgcn_sched_barrier(0);
#pragma unroll
            for (int j = 0; j < 4; ++j) {
                int row = j * 4 + wv;
                *(bf16x8*)&hbh[row * 512 + ((l ^ (row & 7)) * 8)] = hg[j];
            }
            __syncthreads();
#pragma unroll
            for (int m = 0; m < 16; ++m) {
                int G = m * 4 + khi;
                bf16x8 B = *(const bf16x8*)&hbh[colb * 512 + ((G ^ (colb & 7)) * 8)];
                accA = __builtin_amdgcn_mfma_f32_16x16x32_bf16(whA[m], B, accA, 0, 0, 0);
            }
        }
        if (wv != 0) {
#pragma unroll
            for (int j = 0; j < 4; ++j)
                xch[(wv - 1) * 256 + (khi * 4 + j) * 16 + colb] = accA[j];
        }
        __syncthreads();
        if (wv == 0) {
            unsigned short h4[4];
            float p = 0.f;
#pragma unroll
            for (int j = 0; j < 4; ++j) {
                int rr = khi * 4 + j;
                float gi = accA[j];
                float gf = xch[0 * 256 + rr * 16 + colb];
                float gg = xch[1 * 256 + rr * 16 + colb];
                float go = xch[2 * 256 + rr * 16 + colb];
                float c2 = fsigm(gf) * cst[j] + fsigm(gi) * ftanh(gg);
                cst[j] = c2;
                float h = fsigm(go) * ftanh(c2);
                h4[j] = f2bf(h);
                p += h * w2v[j];
            }
            u64 hq = (u64)h4[0] | ((u64)h4[1] << 16) | ((u64)h4[2] << 32) | ((u64)h4[3] << 48);
            size_t hoff = ((size_t)((dir * 2 + (n & 1)) * 16 + colb)) * 512 + d0 + khi * 4;
            asm volatile("global_store_dwordx2 %0, %1, off sc0 sc1"
                         :: "v"(hX + hoff), "v"(hq) : "memory");
            p += __shfl_xor(p, 16);
            p += __shfl_xor(p, 32);
            if (l < 16)
                part[((size_t)((dir * 32 + slice) * 16) + l) * TU + t] = p;
            asm volatile("s_waitcnt vmcnt(0)" ::: "memory");  // h visible before prog bump
            if (l == 0) {
                int nv = n + 1;
                asm volatile("global_store_dword %0, %1, off sc0 sc1"
                             :: "v"(myprog), "v"(nv) : "memory");
            }
        }
        // next-step input dot: off the waited path, overlaps other WGs' progress
        accA = (n + 1 < TU) ? idot(n + 1) : bias;
    }
}

// ---------------- K6: reduce us partials, activation, pre-norm ----------------
__global__ void k_us_reduce(const float* __restrict__ part, const float* __restrict__ ob2,
                            const float* __restrict__ mask, float* __restrict__ usA,
                            float* __restrict__ csum) {
    int b = blockIdx.x, ch = blockIdx.y;
    int t = ch * 256 + threadIdx.x;
    float s = 0.f;
#pragma unroll 8
    for (int p = 0; p < 64; ++p) s += part[((size_t)p * Bz + b) * TU + t];
    float u = sigm(s + ob2[0]);
    float ua = fmaxf(u * SM2c - NT2c, 0.f) * mask[b * Sz + t / 3];
    usA[b * TU + t] = ua;
    __shared__ float red[256];
    red[threadIdx.x] = ua;
    __syncthreads();
    for (int off = 128; off >= 1; off >>= 1) {
        if (threadIdx.x < off) red[threadIdx.x] += red[threadIdx.x + off];
        __syncthreads();
    }
    if (threadIdx.x == 0) csum[b * 6 + ch] = red[0];
}

// ---------------- K7: normalize + peak scan (serial per batch) ----------------
__global__ void k_us_scan(const float* __restrict__ usA, const float* __restrict__ csum,
                          float* __restrict__ out) {
    __shared__ float ubuf[TU];
    int b = blockIdx.x;
    for (int t = threadIdx.x; t < TU; t += 64) ubuf[t] = usA[b * TU + t];
    __syncthreads();
    if (threadIdx.x == 0) {
        float tot = 0.f;
        for (int c = 0; c < 6; ++c) tot += csum[b * 6 + c];
        float scale = out[TOK_OFF + b] / tot;
        float integ = 0.f;
        const float th = THRESHc - 0.0001f;
        for (int t = 0; t < TU; ++t) {
            float ua = ubuf[t] * scale;
            out[USA_OFF + b * TU + t] = ua;
            integ += ua;
            out[USP_OFF + b * TU + t] = integ;
            if (integ >= th) integ -= th;
        }
    }
}

// ---------------- host ----------------
extern "C" void kernel_launch(void* const* d_in, const int* in_sizes, int n_in,
                              void* d_out, int out_size, void* d_ws, size_t ws_size,
                              hipStream_t stream) {
    const float* hidden = (const float*)d_in[0];
    const float* mask   = (const float*)d_in[1];
    const float* conv_w = (const float*)d_in[2];
    const float* conv_b = (const float*)d_in[3];
    const float* out_w  = (const float*)d_in[4];
    const float* out_b  = (const float*)d_in[5];
    const float* up_w   = (const float*)d_in[6];
    const float* up_b   = (const float*)d_in[7];
    const float* w_ih_f = (const float*)d_in[8];
    const float* w_hh_f = (const float*)d_in[9];
    const float* b_ih_f = (const float*)d_in[10];
    const float* b_hh_f = (const float*)d_in[11];
    const float* w_ih_b = (const float*)d_in[12];
    const float* w_hh_b = (const float*)d_in[13];
    const float* b_ih_b = (const float*)d_in[14];
    const float* b_hh_b = (const float*)d_in[15];
    const float* out2_w = (const float*)d_in[16];
    const float* out2_b = (const float*)d_in[17];
    float* out = (float*)d_out;
    float* ws = (float*)d_ws;

    // workspace layout (float slots), total ~8.47M floats = 33.9 MB
    float* wt     = ws + 0;              // 786,432
    float* upt    = ws + 786432;         // 786,432
    float* part   = ws + 1572864;        // 1,572,864
    float* gconst = ws + 3145728;        // 4096
    float* alph_s = ws + 3149824;        // 8192
    float* sc_cur = ws + 3158016;        // 8208
    float* sc_res = ws + 3166224;        // 8208
    int*   sc_dst = (int*)(ws + 3174432);            // 8208
    unsigned short* hX = (unsigned short*)(ws + 3182640);    // 32768 shorts
    float* usA    = ws + 3199024;        // 24576
    float* csum   = ws + 3223600;        // 96
    int*   prog   = (int*)(ws + 3223696);            // 1024 ints (2*32 counters, 64B stride)
    unsigned short* Mh = (unsigned short*)(ws + 3224720);    // 6,291,456 shorts
    unsigned short* Hs = (unsigned short*)(ws + 6370448);    // 4,194,304 shorts

    hipMemsetAsync(out, 0, (size_t)Bz * T1 * Dz * sizeof(float), stream);   // embeds region
    hipMemsetAsync(prog, 0, 1024 * sizeof(int), stream);

    k_transpose_convw<<<dim3(8, 24), 256, 0, stream>>>(conv_w, wt);
    k_transpose_upw<<<dim3(8, 24), 256, 0, stream>>>(up_w, upt);
    k_gconst<<<16, 256, 0, stream>>>(w_ih_f, b_ih_f, b_hh_f, w_ih_b, b_ih_b, b_hh_b, up_b, gconst);
    k_M<<<dim3(8, 32, 6), 256, 0, stream>>>(w_ih_f, w_ih_b, upt, Mh);
    k_Hbf<<<4096, 256, 0, stream>>>(hidden, Hs);
    k_conv_alpha<<<dim3(16, 32), 256, 0, stream>>>(hidden, wt, conv_b, out_w, out_b, mask, alph_s);
    k_cif_scan<<<1, 256, 0, stream>>>(alph_s, mask, out, sc_cur, sc_res, sc_dst);
    k_cif_frames<<<dim3(16, 2), 256, 0, stream>>>(hidden, sc_cur, sc_res, sc_dst, out);

    {
        void* args[] = { (void*)&Mh, (void*)&Hs, (void*)&w_hh_f, (void*)&w_hh_b,
                         (void*)&gconst, (void*)&out2_w, (void*)&hX, (void*)&part,
                         (void*)&prog };
        hipLaunchCooperativeKernel(reinterpret_cast<void*>(&k_lstm), dim3(64), dim3(256),
                                   args, 0, stream);
    }

    k_us_reduce<<<dim3(16, 6), 256, 0, stream>>>(part, out2_b, mask, usA, csum);
    k_us_scan<<<16, 64, 0, stream>>>(usA, csum, out);
}